// Round 12
// baseline (1670.116 us; speedup 1.0000x reference)
//
#include <hip/hip_runtime.h>
#include <hip/hip_bf16.h>
#include <cstdint>

// Problem constants
constexpr int NB_ = 32;     // batch
constexpr int NS_ = 512;    // text length S
constexpr int NT_ = 2048;   // mel length T
constexpr int DMEL = 80;    // embedding dim

// ---------------- workspace layout ----------------
constexpr size_t P = 134217728ull;  // persistent block base
constexpr size_t PO_TE   = 0ull;
constexpr size_t PO_ME   = 5242880ull;
constexpr size_t PO_NA   = 26214400ull;
constexpr size_t PO_NB   = 26279936ull;
constexpr size_t PO_M    = 26542080ull;
constexpr size_t PO_RZ   = 26804224ull;
constexpr size_t PO_W1   = 27066368ull;
constexpr size_t PO_W2   = 28639232ull;
constexpr size_t PO_W3   = 28803072ull;
constexpr size_t PO_W4   = 28956672ull;
constexpr size_t PO_W5   = 29110272ull;
constexpr size_t PO_BIAS = 29135872ull;
constexpr size_t PO_DIR  = 29139968ull;
constexpr size_t PO_IDX  = 33334272ull;
constexpr size_t PO_FLAG = 33334400ull;
constexpr size_t FULL_NEED = P + 33334528ull;

constexpr int BO_T1 = 0, BO_T2 = 512, BO_M1 = 592, BO_M2 = 752, BO_M3 = 832;

// ---------------- dtype detect: bf16 vs f32 probe on text ----------------
__global__ void k_detect(const uint32_t* __restrict__ w, int* __restrict__ flag) {
  __shared__ int red[256];
  const int tid = threadIdx.x;
  int cnt = 0;
  for (int i = tid; i < 4096; i += 256) {
    uint32_t e = (w[i] >> 7) & 0xFFu;
    cnt += (e >= 119u && e <= 129u) ? 1 : 0;
  }
  red[tid] = cnt;
  __syncthreads();
  for (int s = 128; s > 0; s >>= 1) {
    if (tid < s) red[tid] += red[tid + s];
    __syncthreads();
  }
  if (tid == 0) *flag = (red[0] > 2048) ? 1 : 0;
}

// ---------------- flag-branched convert to f32 ----------------
__global__ void k_cvt(const void* __restrict__ in, float* __restrict__ out, int n,
                      const int* __restrict__ flag) {
  const int i = blockIdx.x * 256 + threadIdx.x;
  if (i >= n) return;
  if (*flag) {
    uint16_t u = ((const uint16_t*)in)[i];
    out[i] = __uint_as_float((uint32_t)u << 16);
  } else {
    out[i] = ((const float*)in)[i];
  }
}

// ---------------- weight transpose ----------------
__global__ void k_wtrans(const void* __restrict__ w, float* __restrict__ wT,
                         int CO, int CI, int KW, int total, const int* __restrict__ flag) {
  int id = blockIdx.x * 256 + threadIdx.x;
  if (id >= total) return;
  int co = id % CO;
  int rest = id / CO;
  int ci = rest % CI;
  int tap = rest / CI;
  int src = (co * CI + ci) * KW + tap;
  if (*flag) {
    uint16_t u = ((const uint16_t*)w)[src];
    wT[id] = __uint_as_float((uint32_t)u << 16);
  } else {
    wT[id] = ((const float*)w)[src];
  }
}

// ---------------- conv1d as implicit GEMM (pure f32) ----------------
template <int CIN, int KW, int COUT, int NTILE, int NR, int KC, int LOG2L, int ACT, bool MASK>
__global__ __launch_bounds__(256) void k_conv(const float* __restrict__ x,
                                              const float* __restrict__ wT,
                                              const float* __restrict__ bias,
                                              float* __restrict__ y,
                                              const int* __restrict__ lenArr) {
  constexpr int L = 1 << LOG2L;
  constexpr int PAD = (KW - 1) / 2;
  constexpr int MT = 128;
  constexpr int APAD = 132;
  constexpr int BPAD = NTILE + 4;
  __shared__ float As[KC][APAD];
  __shared__ float Bs[KC][BPAD];

  const int tid = threadIdx.x;
  const int tx = tid & 15;
  const int ty = tid >> 4;
  constexpr int NBLK = COUT / NTILE;
  const int m0 = (blockIdx.x / NBLK) * MT;
  const int n0 = (blockIdx.x % NBLK) * NTILE;

  float acc[8][NR];
#pragma unroll
  for (int i = 0; i < 8; ++i)
#pragma unroll
    for (int j = 0; j < NR; ++j) acc[i][j] = 0.f;

  for (int tap = 0; tap < KW; ++tap) {
    for (int k0 = 0; k0 < CIN; k0 += KC) {
      __syncthreads();
      constexpr int AF4 = MT * KC / 4;
      constexpr int F4R = KC / 4;
      for (int f = tid; f < AF4; f += 256) {
        int row = f / F4R;
        int ko = (f % F4R) * 4;
        int r = m0 + row;
        int b = r >> LOG2L;
        int pos = (r & (L - 1)) + tap - PAD;
        float4 v = make_float4(0.f, 0.f, 0.f, 0.f);
        if (pos >= 0 && pos < L)
          v = *reinterpret_cast<const float4*>(
              &x[((size_t)(b << LOG2L) + pos) * CIN + k0 + ko]);
        As[ko + 0][row] = v.x;
        As[ko + 1][row] = v.y;
        As[ko + 2][row] = v.z;
        As[ko + 3][row] = v.w;
      }
      constexpr int BF4 = KC * NTILE / 4;
      constexpr int BF4R = NTILE / 4;
      for (int f = tid; f < BF4; f += 256) {
        int kk = f / BF4R;
        int no = (f % BF4R) * 4;
        float4 v = *reinterpret_cast<const float4*>(
            &wT[((size_t)(tap * CIN + k0 + kk)) * COUT + n0 + no]);
        *reinterpret_cast<float4*>(&Bs[kk][no]) = v;
      }
      __syncthreads();
#pragma unroll 8
      for (int kk = 0; kk < KC; ++kk) {
        float4 a0 = *reinterpret_cast<const float4*>(&As[kk][ty * 8]);
        float4 a1 = *reinterpret_cast<const float4*>(&As[kk][ty * 8 + 4]);
        float av[8] = {a0.x, a0.y, a0.z, a0.w, a1.x, a1.y, a1.z, a1.w};
        float bv[NR];
#pragma unroll
        for (int j = 0; j < NR; ++j) bv[j] = Bs[kk][tx * NR + j];
#pragma unroll
        for (int i = 0; i < 8; ++i)
#pragma unroll
          for (int j = 0; j < NR; ++j) acc[i][j] = fmaf(av[i], bv[j], acc[i][j]);
      }
    }
  }
#pragma unroll
  for (int i = 0; i < 8; ++i) {
    int r = m0 + ty * 8 + i;
    int b = r >> LOG2L;
    int pos = r & (L - 1);
    bool zero = MASK && (pos >= lenArr[b]);
#pragma unroll
    for (int j = 0; j < NR; ++j) {
      int c = n0 + tx * NR + j;
      float v = acc[i][j] + bias[c];
      if (ACT == 1) v = fmaxf(v, 0.f);
      if (ACT == 2) v = (v >= 0.f) ? v : 0.01f * v;
      if (zero) v = 0.f;
      y[(size_t)r * COUT + c] = v;
    }
  }
}

// ---------------- row squared-norms ----------------
__global__ void k_norms(const float* __restrict__ e, float* __restrict__ out, int rows) {
  int tid = blockIdx.x * 256 + threadIdx.x;
  int row = tid >> 2, sub = tid & 3;
  if (row >= rows) return;
  const float* p = e + (size_t)row * DMEL;
  float s = 0.f;
#pragma unroll
  for (int j = 0; j < 5; ++j) {
    float4 v = *reinterpret_cast<const float4*>(&p[(sub + 4 * j) * 4]);
    s = fmaf(v.x, v.x, fmaf(v.y, v.y, fmaf(v.z, v.z, fmaf(v.w, v.w, s))));
  }
  s += __shfl_xor(s, 1);
  s += __shfl_xor(s, 2);
  if (sub == 0) out[row] = s;
}

// ---------------- softmax stats by recomputation ----------------
__global__ __launch_bounds__(256) void k_stats2(
    const float* __restrict__ te, const float* __restrict__ me,
    const float* __restrict__ na, const float* __restrict__ nb,
    const int* __restrict__ src_len, const int* __restrict__ mel_len,
    float* __restrict__ marr, float* __restrict__ rzarr) {
  const int b = blockIdx.x >> 5;
  const int t0 = (blockIdx.x & 31) << 6;
  __shared__ float Bt[DMEL][68];
  __shared__ float At[DMEL][68];
  __shared__ float redm[16][64];
  __shared__ float redz[16][64];
  const int tid = threadIdx.x;
  for (int f = tid; f < 64 * 20; f += 256) {
    int row = f / 20, ko = (f % 20) << 2;
    float4 v = *reinterpret_cast<const float4*>(
        &me[((size_t)b * NT_ + t0 + row) * DMEL + ko]);
    Bt[ko][row] = v.x; Bt[ko + 1][row] = v.y; Bt[ko + 2][row] = v.z; Bt[ko + 3][row] = v.w;
  }
  const int tx = tid & 15, sy = tid >> 4;
  const int sl = src_len[b], ml = mel_len[b];
  const float NEGINF = -__builtin_inff();
  float nbv[4], mACC[4], zACC[4];
#pragma unroll
  for (int j = 0; j < 4; ++j) {
    nbv[j] = nb[b * NT_ + t0 + (tx << 2) + j];
    mACC[j] = NEGINF;
    zACC[j] = 0.f;
  }
  for (int c = 0; c < 8; ++c) {
    const int s0 = c << 6;
    __syncthreads();
    for (int f = tid; f < 64 * 20; f += 256) {
      int row = f / 20, ko = (f % 20) << 2;
      float4 v = *reinterpret_cast<const float4*>(
          &te[((size_t)b * NS_ + s0 + row) * DMEL + ko]);
      At[ko][row] = v.x; At[ko + 1][row] = v.y; At[ko + 2][row] = v.z; At[ko + 3][row] = v.w;
    }
    __syncthreads();
    float acc[4][4];
#pragma unroll
    for (int i = 0; i < 4; ++i)
#pragma unroll
      for (int j = 0; j < 4; ++j) acc[i][j] = 0.f;
#pragma unroll 8
    for (int kk = 0; kk < DMEL; ++kk) {
      float4 a = *reinterpret_cast<const float4*>(&At[kk][sy << 2]);
      float4 bb = *reinterpret_cast<const float4*>(&Bt[kk][tx << 2]);
      float av[4] = {a.x, a.y, a.z, a.w}, bv[4] = {bb.x, bb.y, bb.z, bb.w};
#pragma unroll
      for (int i = 0; i < 4; ++i)
#pragma unroll
        for (int j = 0; j < 4; ++j) acc[i][j] = fmaf(av[i], bv[j], acc[i][j]);
    }
    float nav[4];
#pragma unroll
    for (int i = 0; i < 4; ++i) nav[i] = na[b * NS_ + s0 + (sy << 2) + i];
#pragma unroll
    for (int j = 0; j < 4; ++j) {
      const bool tvalid = (t0 + (tx << 2) + j) < ml;
      float ov[4];
      float mNew = mACC[j];
#pragma unroll
      for (int i = 0; i < 4; ++i) {
        float d2 = (nav[i] + nbv[j]) - 2.0f * acc[i][j];
        float dist = sqrtf(fmaxf(d2, 1e-12f));
        bool valid = ((s0 + (sy << 2) + i) < sl) && tvalid;
        ov[i] = valid ? -dist : -1e9f;
        mNew = fmaxf(mNew, ov[i]);
      }
      float scale = expf(mACC[j] - mNew);
      float zadd = 0.f;
#pragma unroll
      for (int i = 0; i < 4; ++i) zadd += expf(ov[i] - mNew);
      zACC[j] = zACC[j] * scale + zadd;
      mACC[j] = mNew;
    }
  }
#pragma unroll
  for (int j = 0; j < 4; ++j) {
    redm[sy][(tx << 2) + j] = mACC[j];
    redz[sy][(tx << 2) + j] = zACC[j];
  }
  __syncthreads();
  if (tid < 64) {
    float M = NEGINF, Z = 0.f;
#pragma unroll
    for (int y = 0; y < 16; ++y) {
      float m = redm[y][tid], z = redz[y][tid];
      float Mn = fmaxf(M, m);
      Z = Z * expf(M - Mn) + z * expf(m - Mn);
      M = Mn;
    }
    marr[b * NT_ + t0 + tid] = M;
    rzarr[b * NT_ + t0 + tid] = 1.0f / Z;
  }
}

// ---------------- finalize: soft/rev f32 out + f32 val for DP ----------------
__global__ __launch_bounds__(256) void k_final3(
    const float* __restrict__ te, const float* __restrict__ me,
    const float* __restrict__ na, const float* __restrict__ nb,
    const float* __restrict__ marr, const float* __restrict__ rzarr,
    const int* __restrict__ src_len, const int* __restrict__ mel_len,
    float* __restrict__ val,
    float* __restrict__ soft, float* __restrict__ rev) {
  const int idx = blockIdx.x;
  const int tt = idx & 31;
  const int st = (idx >> 5) & 7;
  const int b = idx >> 8;
  const int s0 = st << 6, t0 = tt << 6;
  __shared__ float At[DMEL][68];
  __shared__ float Bt[DMEL][68];
  __shared__ float pl[64][65];
  const int tid = threadIdx.x;
  for (int f = tid; f < 64 * 20; f += 256) {
    int row = f / 20, ko = (f % 20) << 2;
    float4 v = *reinterpret_cast<const float4*>(
        &te[((size_t)b * NS_ + s0 + row) * DMEL + ko]);
    At[ko][row] = v.x; At[ko + 1][row] = v.y; At[ko + 2][row] = v.z; At[ko + 3][row] = v.w;
  }
  for (int f = tid; f < 64 * 20; f += 256) {
    int row = f / 20, ko = (f % 20) << 2;
    float4 v = *reinterpret_cast<const float4*>(
        &me[((size_t)b * NT_ + t0 + row) * DMEL + ko]);
    Bt[ko][row] = v.x; Bt[ko + 1][row] = v.y; Bt[ko + 2][row] = v.z; Bt[ko + 3][row] = v.w;
  }
  __syncthreads();
  const int tx = tid & 15, sy = tid >> 4;
  float acc[4][4];
#pragma unroll
  for (int i = 0; i < 4; ++i)
#pragma unroll
    for (int j = 0; j < 4; ++j) acc[i][j] = 0.f;
#pragma unroll 8
  for (int kk = 0; kk < DMEL; ++kk) {
    float4 a = *reinterpret_cast<const float4*>(&At[kk][sy << 2]);
    float4 bb = *reinterpret_cast<const float4*>(&Bt[kk][tx << 2]);
    float av[4] = {a.x, a.y, a.z, a.w}, bv[4] = {bb.x, bb.y, bb.z, bb.w};
#pragma unroll
    for (int i = 0; i < 4; ++i)
#pragma unroll
      for (int j = 0; j < 4; ++j) acc[i][j] = fmaf(av[i], bv[j], acc[i][j]);
  }
  const int sl = src_len[b], ml = mel_len[b];
  float nav[4], nbv[4];
#pragma unroll
  for (int i = 0; i < 4; ++i) nav[i] = na[b * NS_ + s0 + (sy << 2) + i];
#pragma unroll
  for (int j = 0; j < 4; ++j) nbv[j] = nb[b * NT_ + t0 + (tx << 2) + j];
#pragma unroll
  for (int j = 0; j < 4; ++j) {
    const int t = t0 + (tx << 2) + j;
    const bool tvalid = t < ml;
    const float mv = marr[b * NT_ + t];
    const float rzv = rzarr[b * NT_ + t];
    float pv[4];
#pragma unroll
    for (int i = 0; i < 4; ++i) {
      float d2 = (nav[i] + nbv[j]) - 2.0f * acc[i][j];
      float dist = sqrtf(fmaxf(d2, 1e-12f));
      bool valid = ((s0 + (sy << 2) + i) < sl) && tvalid;
      float ov = valid ? -dist : -1e9f;
      float p = tvalid ? expf(ov - mv) * rzv : 0.f;
      pv[i] = p;
      pl[(tx << 2) + j][(sy << 2) + i] = p;
    }
    float4 o = make_float4(pv[0], pv[1], pv[2], pv[3]);
    *reinterpret_cast<float4*>(&val[((size_t)b * NT_ + t) * NS_ + s0 + (sy << 2)]) = o;
  }
  __syncthreads();
  const int lane = tid & 63, w = tid >> 6;
#pragma unroll 4
  for (int i = 0; i < 16; ++i) {
    const int s_loc = (w << 4) + i;
    const int s = s0 + s_loc;
    float p = pl[lane][s_loc];
    size_t o = ((size_t)b * NS_ + s) * NT_ + t0 + lane;
    soft[o] = p;
    bool r = (s >= sl) || ((t0 + lane) >= ml);
    rev[o] = r ? 1.0f : 0.0f;
  }
}

// lane i <- lane i-1 via DPP wave_shr:1 (VALU, no LDS pipe). Lane 0 -> 0.
__device__ __forceinline__ float dp_shr1(float x) {
  int r = __builtin_amdgcn_update_dpp(0, __float_as_int(x), 0x138, 0xF, 0xF, true);
  return __int_as_float(r);
}

// ---------------- DP forward scan: single wave, register-pipelined loads ------
// No LDS, no barriers, no producer waves. 4 static register stages (4 rows x
// 2 float4 each); group g uses stage g%4 and reloads it with group g+4 --
// prefetch distance = 16 rows (~1400 cyc of compute) with compiler-counted
// vmcnt per stage (all register names static; rule 20). De-interleaved lane
// ownership: lane l holds floats [8l..8l+8).
#define DP_LOADG(SA, SB, grp)                                                 \
  do {                                                                        \
    _Pragma("unroll") for (int rr = 0; rr < 4; ++rr) {                        \
      const float* gp = base + (size_t)((grp) * 4 + rr) * NS_;                \
      SA[rr] = *reinterpret_cast<const float4*>(gp);                          \
      SB[rr] = *reinterpret_cast<const float4*>(gp + 4);                      \
    }                                                                         \
  } while (0)

#define DP_ROW(ca, cb, tt_, MASKED)                                           \
  do {                                                                        \
    const int t_ = (tt_);                                                     \
    const int sh = t_ & 31;                                                   \
    if (t_ < ml) {                                                            \
      float up = dp_shr1(v[7]);                                               \
      float prev = (lane == 0) ? NEGINF : up;                                 \
      float cc[8] = {ca.x, ca.y, ca.z, ca.w, cb.x, cb.y, cb.z, cb.w};         \
      _Pragma("unroll") for (int j = 0; j < 8; ++j) {                         \
        float cur = v[j];                                                     \
        bool keep = cur >= prev;                                              \
        float vm = fmaxf(cur, prev);                                          \
        float vn;                                                             \
        if (MASKED) {                                                         \
          int s = (lane << 3) + j;                                            \
          vn = (s <= t_) ? vm + cc[j] : NEGINF;                               \
        } else {                                                              \
          vn = vm + cc[j];                                                    \
        }                                                                     \
        bw[j] |= (keep ? 1u : invm[j]) << sh;                                 \
        v[j] = vn;                                                            \
        prev = cur;                                                           \
      }                                                                       \
    } else {                                                                  \
      _Pragma("unroll") for (int j = 0; j < 8; ++j) bw[j] |= 1u << sh;        \
    }                                                                         \
  } while (0)

#define DP_STEP(SA, SB, grp, MASKED)                                          \
  do {                                                                        \
    DP_ROW(SA[0], SB[0], (grp) * 4 + 0, MASKED);                              \
    DP_ROW(SA[1], SB[1], (grp) * 4 + 1, MASKED);                              \
    DP_ROW(SA[2], SB[2], (grp) * 4 + 2, MASKED);                              \
    DP_ROW(SA[3], SB[3], (grp) * 4 + 3, MASKED);                              \
    if ((grp) + 4 < 512) DP_LOADG(SA, SB, (grp) + 4);                         \
  } while (0)

__global__ __launch_bounds__(64, 1) void k_dp(const float* __restrict__ val,
                                              const int* __restrict__ src_len,
                                              const int* __restrict__ mel_len,
                                              uint32_t* __restrict__ dir) {
  const int b = blockIdx.x;
  const int lane = threadIdx.x;
  const float* base = val + (size_t)b * NT_ * NS_ + (lane << 3);
  const int sl = src_len[b];
  const int ml = mel_len[b];
  const float NEGINF = -__builtin_inff();

  float v[8];
  uint32_t bw[8], invm[8];
#pragma unroll
  for (int j = 0; j < 8; ++j) {
    v[j] = 0.0f;
    bw[j] = 0u;
    int s = (lane << 3) + j;
    invm[j] = (s < sl) ? 0u : 1u;
  }

  float4 s0a[4], s0b[4], s1a[4], s1b[4], s2a[4], s2b[4], s3a[4], s3b[4];
  DP_LOADG(s0a, s0b, 0);
  DP_LOADG(s1a, s1b, 1);
  DP_LOADG(s2a, s2b, 2);
  DP_LOADG(s3a, s3b, 3);

  for (int m = 0; m < 64; ++m) {  // 32 rows (8 groups) per iteration
    const int G = m << 3;
    if (m < 16) {  // t < 512: (s<=t) clamp active
      DP_STEP(s0a, s0b, G + 0, true);
      DP_STEP(s1a, s1b, G + 1, true);
      DP_STEP(s2a, s2b, G + 2, true);
      DP_STEP(s3a, s3b, G + 3, true);
      DP_STEP(s0a, s0b, G + 4, true);
      DP_STEP(s1a, s1b, G + 5, true);
      DP_STEP(s2a, s2b, G + 6, true);
      DP_STEP(s3a, s3b, G + 7, true);
    } else {
      DP_STEP(s0a, s0b, G + 0, false);
      DP_STEP(s1a, s1b, G + 1, false);
      DP_STEP(s2a, s2b, G + 2, false);
      DP_STEP(s3a, s3b, G + 3, false);
      DP_STEP(s0a, s0b, G + 4, false);
      DP_STEP(s1a, s1b, G + 5, false);
      DP_STEP(s2a, s2b, G + 6, false);
      DP_STEP(s3a, s3b, G + 7, false);
    }
#pragma unroll
    for (int j = 0; j < 8; ++j) {
      dir[((size_t)(b * NS_) + (lane << 3) + j) * 64 + m] = bw[j];
      bw[j] = 0u;
    }
  }
}

// ---------------- backtrack (two half-T phases) ----------------
__global__ __launch_bounds__(256) void k_backtrack(
    const uint32_t* __restrict__ dir, const int* __restrict__ src_len,
    const int* __restrict__ mel_len, float* __restrict__ hard,
    int* __restrict__ idxio, int phase) {
  __shared__ uint32_t dl[NS_ * 32];
  const int b = blockIdx.x, tid = threadIdx.x;
  const uint32_t* db = dir + (size_t)b * NS_ * 64;
  const int woff = phase ? 0 : 32;
  for (int f = tid; f < 4096; f += 256) {
    int s = f >> 3;
    int wo = (f & 7) << 2;
    *reinterpret_cast<uint4*>(&dl[s * 32 + wo]) =
        *reinterpret_cast<const uint4*>(&db[s * 64 + woff + wo]);
  }
  __syncthreads();
  if (tid == 0) {
    const int ml = mel_len[b];
    int idx = phase ? idxio[b] : (src_len[b] - 1);
    if (idx < 0) idx = 0;
    if (idx > NS_ - 1) idx = NS_ - 1;
    const int thi = phase ? 1023 : 2047;
    const int tlo = phase ? 0 : 1024;
    int cw = -1, ci = -1;
    uint32_t w = 0;
    for (int t = thi; t >= tlo; --t) {
      int wi = t >> 5;
      if (wi != cw || idx != ci) {
        w = dl[idx * 32 + (wi - woff)];
        cw = wi;
        ci = idx;
      }
      if (t < ml) hard[((size_t)(b * NS_) + idx) * NT_ + t] = 1.0f;
      int step = (int)((w >> (t & 31)) & 1) - 1;
      idx += step;
      if (idx < 0) idx = 0;
    }
    if (!phase) idxio[b] = idx;
  }
}

// ---------------- host launch ----------------
extern "C" void kernel_launch(void* const* d_in, const int* in_sizes, int n_in,
                              void* d_out, int out_size, void* d_ws, size_t ws_size,
                              hipStream_t stream) {
  if (n_in != 17) return;
  if (ws_size < FULL_NEED) return;

  const void* text = d_in[0];
  const void* mel = d_in[1];
  const int* src_len = (const int*)d_in[2];
  const int* mel_len = (const int*)d_in[3];
  const void* tw1 = d_in[7];
  const void* tb1 = d_in[8];
  const void* tw2 = d_in[9];
  const void* tb2 = d_in[10];
  const void* mw1 = d_in[11];
  const void* mb1 = d_in[12];
  const void* mw2 = d_in[13];
  const void* mb2 = d_in[14];
  const void* mw3 = d_in[15];
  const void* mb3 = d_in[16];

  char* w8 = (char*)d_ws;
  float* mel_f32 = (float*)(w8 + 0);
  float* melh1 = (float*)(w8 + 20971520ull);
  float* mh2 = (float*)(w8 + 62914560ull);
  float* text_f32 = (float*)(w8 + 83886080ull);
  float* texth1 = (float*)(w8 + 100663296ull);
  float* val = (float*)(w8 + 0);

  float* te = (float*)(w8 + P + PO_TE);
  float* me = (float*)(w8 + P + PO_ME);
  float* na = (float*)(w8 + P + PO_NA);
  float* nb = (float*)(w8 + P + PO_NB);
  float* marr = (float*)(w8 + P + PO_M);
  float* rzarr = (float*)(w8 + P + PO_RZ);
  float* wt1 = (float*)(w8 + P + PO_W1);
  float* wt2 = (float*)(w8 + P + PO_W2);
  float* wt3 = (float*)(w8 + P + PO_W3);
  float* wt4 = (float*)(w8 + P + PO_W4);
  float* wt5 = (float*)(w8 + P + PO_W5);
  float* biasb = (float*)(w8 + P + PO_BIAS);
  uint32_t* dir = (uint32_t*)(w8 + P + PO_DIR);
  int* idxio = (int*)(w8 + P + PO_IDX);
  int* flag = (int*)(w8 + P + PO_FLAG);

  // outputs are float32
  float* soft = (float*)d_out;
  float* hard = soft + (size_t)NB_ * NS_ * NT_;
  float* rev = soft + 2 * (size_t)NB_ * NS_ * NT_;

  // dtype detect + converts
  k_detect<<<1, 256, 0, stream>>>((const uint32_t*)text, flag);
  k_cvt<<<(NB_ * NS_ * 256 + 255) / 256, 256, 0, stream>>>(text, text_f32, NB_ * NS_ * 256, flag);
  k_cvt<<<(NB_ * NT_ * 80 + 255) / 256, 256, 0, stream>>>(mel, mel_f32, NB_ * NT_ * 80, flag);
  k_cvt<<<2, 256, 0, stream>>>(tb1, biasb + BO_T1, 512, flag);
  k_cvt<<<1, 256, 0, stream>>>(tb2, biasb + BO_T2, 80, flag);
  k_cvt<<<1, 256, 0, stream>>>(mb1, biasb + BO_M1, 160, flag);
  k_cvt<<<1, 256, 0, stream>>>(mb2, biasb + BO_M2, 80, flag);
  k_cvt<<<1, 256, 0, stream>>>(mb3, biasb + BO_M3, 80, flag);

  // weight transposes
  k_wtrans<<<(512 * 256 * 3 + 255) / 256, 256, 0, stream>>>(tw1, wt1, 512, 256, 3, 512 * 256 * 3, flag);
  k_wtrans<<<(80 * 512 + 255) / 256, 256, 0, stream>>>(tw2, wt2, 80, 512, 1, 80 * 512, flag);
  k_wtrans<<<(160 * 80 * 3 + 255) / 256, 256, 0, stream>>>(mw1, wt3, 160, 80, 3, 160 * 80 * 3, flag);
  k_wtrans<<<(80 * 160 * 3 + 255) / 256, 256, 0, stream>>>(mw2, wt4, 80, 160, 3, 80 * 160 * 3, flag);
  k_wtrans<<<(80 * 80 + 255) / 256, 256, 0, stream>>>(mw3, wt5, 80, 80, 1, 80 * 80, flag);

  // encoders (pure f32)
  k_conv<80, 3, 160, 80, 5, 16, 11, 2, false><<<512 * 2, 256, 0, stream>>>(mel_f32, wt3, biasb + BO_M1, melh1, nullptr);
  k_conv<160, 3, 80, 80, 5, 32, 11, 2, false><<<512 * 1, 256, 0, stream>>>(melh1, wt4, biasb + BO_M2, mh2, nullptr);
  k_conv<80, 1, 80, 80, 5, 16, 11, 0, true><<<512 * 1, 256, 0, stream>>>(mh2, wt5, biasb + BO_M3, me, mel_len);
  k_conv<256, 3, 512, 128, 8, 32, 9, 1, false><<<128 * 4, 256, 0, stream>>>(text_f32, wt1, biasb + BO_T1, texth1, nullptr);
  k_conv<512, 1, 80, 80, 5, 32, 9, 0, true><<<128 * 1, 256, 0, stream>>>(texth1, wt2, biasb + BO_T2, te, src_len);

  // norms
  k_norms<<<(NB_ * NS_ * 4) / 256, 256, 0, stream>>>(te, na, NB_ * NS_);
  k_norms<<<(NB_ * NT_ * 4) / 256, 256, 0, stream>>>(me, nb, NB_ * NT_);

  // hard_A zero EARLY so its 128MB write traffic doesn't evict val from L3
  hipMemsetAsync(hard, 0, (size_t)NB_ * NS_ * NT_ * 4, stream);

  // softmax stats + finalize
  k_stats2<<<NB_ * 32, 256, 0, stream>>>(te, me, na, nb, src_len, mel_len, marr, rzarr);
  k_final3<<<NB_ * 8 * 32, 256, 0, stream>>>(te, me, na, nb, marr, rzarr, src_len, mel_len,
                                             val, soft, rev);

  // DP + backtrack
  k_dp<<<NB_, 64, 0, stream>>>(val, src_len, mel_len, dir);
  k_backtrack<<<NB_, 256, 0, stream>>>(dir, src_len, mel_len, hard, idxio, 0);
  k_backtrack<<<NB_, 256, 0, stream>>>(dir, src_len, mel_len, hard, idxio, 1);
}

// Round 13
// 1340.626 us; speedup vs baseline: 1.2458x; 1.2458x over previous
//
#include <hip/hip_runtime.h>
#include <hip/hip_bf16.h>
#include <cstdint>

// Problem constants
constexpr int NB_ = 32;     // batch
constexpr int NS_ = 512;    // text length S
constexpr int NT_ = 2048;   // mel length T
constexpr int DMEL = 80;    // embedding dim

// ---------------- workspace layout ----------------
constexpr size_t P = 134217728ull;  // persistent block base
constexpr size_t PO_TE   = 0ull;
constexpr size_t PO_ME   = 5242880ull;
constexpr size_t PO_NA   = 26214400ull;
constexpr size_t PO_NB   = 26279936ull;
constexpr size_t PO_M    = 26542080ull;
constexpr size_t PO_RZ   = 26804224ull;
constexpr size_t PO_W1   = 27066368ull;
constexpr size_t PO_W2   = 28639232ull;
constexpr size_t PO_W3   = 28803072ull;
constexpr size_t PO_W4   = 28956672ull;
constexpr size_t PO_W5   = 29110272ull;
constexpr size_t PO_BIAS = 29135872ull;
constexpr size_t PO_DIR  = 29139968ull;
constexpr size_t PO_IDX  = 33334272ull;
constexpr size_t PO_FLAG = 33334400ull;
constexpr size_t FULL_NEED = P + 33334528ull;

constexpr int BO_T1 = 0, BO_T2 = 512, BO_M1 = 592, BO_M2 = 752, BO_M3 = 832;

// ---------------- dtype detect: bf16 vs f32 probe on text ----------------
__global__ void k_detect(const uint32_t* __restrict__ w, int* __restrict__ flag) {
  __shared__ int red[256];
  const int tid = threadIdx.x;
  int cnt = 0;
  for (int i = tid; i < 4096; i += 256) {
    uint32_t e = (w[i] >> 7) & 0xFFu;
    cnt += (e >= 119u && e <= 129u) ? 1 : 0;
  }
  red[tid] = cnt;
  __syncthreads();
  for (int s = 128; s > 0; s >>= 1) {
    if (tid < s) red[tid] += red[tid + s];
    __syncthreads();
  }
  if (tid == 0) *flag = (red[0] > 2048) ? 1 : 0;
}

// ---------------- flag-branched convert to f32 ----------------
__global__ void k_cvt(const void* __restrict__ in, float* __restrict__ out, int n,
                      const int* __restrict__ flag) {
  const int i = blockIdx.x * 256 + threadIdx.x;
  if (i >= n) return;
  if (*flag) {
    uint16_t u = ((const uint16_t*)in)[i];
    out[i] = __uint_as_float((uint32_t)u << 16);
  } else {
    out[i] = ((const float*)in)[i];
  }
}

// ---------------- weight transpose ----------------
__global__ void k_wtrans(const void* __restrict__ w, float* __restrict__ wT,
                         int CO, int CI, int KW, int total, const int* __restrict__ flag) {
  int id = blockIdx.x * 256 + threadIdx.x;
  if (id >= total) return;
  int co = id % CO;
  int rest = id / CO;
  int ci = rest % CI;
  int tap = rest / CI;
  int src = (co * CI + ci) * KW + tap;
  if (*flag) {
    uint16_t u = ((const uint16_t*)w)[src];
    wT[id] = __uint_as_float((uint32_t)u << 16);
  } else {
    wT[id] = ((const float*)w)[src];
  }
}

// ---------------- conv1d as implicit GEMM (pure f32) ----------------
template <int CIN, int KW, int COUT, int NTILE, int NR, int KC, int LOG2L, int ACT, bool MASK>
__global__ __launch_bounds__(256) void k_conv(const float* __restrict__ x,
                                              const float* __restrict__ wT,
                                              const float* __restrict__ bias,
                                              float* __restrict__ y,
                                              const int* __restrict__ lenArr) {
  constexpr int L = 1 << LOG2L;
  constexpr int PAD = (KW - 1) / 2;
  constexpr int MT = 128;
  constexpr int APAD = 132;
  constexpr int BPAD = NTILE + 4;
  __shared__ float As[KC][APAD];
  __shared__ float Bs[KC][BPAD];

  const int tid = threadIdx.x;
  const int tx = tid & 15;
  const int ty = tid >> 4;
  constexpr int NBLK = COUT / NTILE;
  const int m0 = (blockIdx.x / NBLK) * MT;
  const int n0 = (blockIdx.x % NBLK) * NTILE;

  float acc[8][NR];
#pragma unroll
  for (int i = 0; i < 8; ++i)
#pragma unroll
    for (int j = 0; j < NR; ++j) acc[i][j] = 0.f;

  for (int tap = 0; tap < KW; ++tap) {
    for (int k0 = 0; k0 < CIN; k0 += KC) {
      __syncthreads();
      constexpr int AF4 = MT * KC / 4;
      constexpr int F4R = KC / 4;
      for (int f = tid; f < AF4; f += 256) {
        int row = f / F4R;
        int ko = (f % F4R) * 4;
        int r = m0 + row;
        int b = r >> LOG2L;
        int pos = (r & (L - 1)) + tap - PAD;
        float4 v = make_float4(0.f, 0.f, 0.f, 0.f);
        if (pos >= 0 && pos < L)
          v = *reinterpret_cast<const float4*>(
              &x[((size_t)(b << LOG2L) + pos) * CIN + k0 + ko]);
        As[ko + 0][row] = v.x;
        As[ko + 1][row] = v.y;
        As[ko + 2][row] = v.z;
        As[ko + 3][row] = v.w;
      }
      constexpr int BF4 = KC * NTILE / 4;
      constexpr int BF4R = NTILE / 4;
      for (int f = tid; f < BF4; f += 256) {
        int kk = f / BF4R;
        int no = (f % BF4R) * 4;
        float4 v = *reinterpret_cast<const float4*>(
            &wT[((size_t)(tap * CIN + k0 + kk)) * COUT + n0 + no]);
        *reinterpret_cast<float4*>(&Bs[kk][no]) = v;
      }
      __syncthreads();
#pragma unroll 8
      for (int kk = 0; kk < KC; ++kk) {
        float4 a0 = *reinterpret_cast<const float4*>(&As[kk][ty * 8]);
        float4 a1 = *reinterpret_cast<const float4*>(&As[kk][ty * 8 + 4]);
        float av[8] = {a0.x, a0.y, a0.z, a0.w, a1.x, a1.y, a1.z, a1.w};
        float bv[NR];
#pragma unroll
        for (int j = 0; j < NR; ++j) bv[j] = Bs[kk][tx * NR + j];
#pragma unroll
        for (int i = 0; i < 8; ++i)
#pragma unroll
          for (int j = 0; j < NR; ++j) acc[i][j] = fmaf(av[i], bv[j], acc[i][j]);
      }
    }
  }
#pragma unroll
  for (int i = 0; i < 8; ++i) {
    int r = m0 + ty * 8 + i;
    int b = r >> LOG2L;
    int pos = r & (L - 1);
    bool zero = MASK && (pos >= lenArr[b]);
#pragma unroll
    for (int j = 0; j < NR; ++j) {
      int c = n0 + tx * NR + j;
      float v = acc[i][j] + bias[c];
      if (ACT == 1) v = fmaxf(v, 0.f);
      if (ACT == 2) v = (v >= 0.f) ? v : 0.01f * v;
      if (zero) v = 0.f;
      y[(size_t)r * COUT + c] = v;
    }
  }
}

// ---------------- row squared-norms ----------------
__global__ void k_norms(const float* __restrict__ e, float* __restrict__ out, int rows) {
  int tid = blockIdx.x * 256 + threadIdx.x;
  int row = tid >> 2, sub = tid & 3;
  if (row >= rows) return;
  const float* p = e + (size_t)row * DMEL;
  float s = 0.f;
#pragma unroll
  for (int j = 0; j < 5; ++j) {
    float4 v = *reinterpret_cast<const float4*>(&p[(sub + 4 * j) * 4]);
    s = fmaf(v.x, v.x, fmaf(v.y, v.y, fmaf(v.z, v.z, fmaf(v.w, v.w, s))));
  }
  s += __shfl_xor(s, 1);
  s += __shfl_xor(s, 2);
  if (sub == 0) out[row] = s;
}

// ---------------- softmax stats by recomputation ----------------
__global__ __launch_bounds__(256) void k_stats2(
    const float* __restrict__ te, const float* __restrict__ me,
    const float* __restrict__ na, const float* __restrict__ nb,
    const int* __restrict__ src_len, const int* __restrict__ mel_len,
    float* __restrict__ marr, float* __restrict__ rzarr) {
  const int b = blockIdx.x >> 5;
  const int t0 = (blockIdx.x & 31) << 6;
  __shared__ float Bt[DMEL][68];
  __shared__ float At[DMEL][68];
  __shared__ float redm[16][64];
  __shared__ float redz[16][64];
  const int tid = threadIdx.x;
  for (int f = tid; f < 64 * 20; f += 256) {
    int row = f / 20, ko = (f % 20) << 2;
    float4 v = *reinterpret_cast<const float4*>(
        &me[((size_t)b * NT_ + t0 + row) * DMEL + ko]);
    Bt[ko][row] = v.x; Bt[ko + 1][row] = v.y; Bt[ko + 2][row] = v.z; Bt[ko + 3][row] = v.w;
  }
  const int tx = tid & 15, sy = tid >> 4;
  const int sl = src_len[b], ml = mel_len[b];
  const float NEGINF = -__builtin_inff();
  float nbv[4], mACC[4], zACC[4];
#pragma unroll
  for (int j = 0; j < 4; ++j) {
    nbv[j] = nb[b * NT_ + t0 + (tx << 2) + j];
    mACC[j] = NEGINF;
    zACC[j] = 0.f;
  }
  for (int c = 0; c < 8; ++c) {
    const int s0 = c << 6;
    __syncthreads();
    for (int f = tid; f < 64 * 20; f += 256) {
      int row = f / 20, ko = (f % 20) << 2;
      float4 v = *reinterpret_cast<const float4*>(
          &te[((size_t)b * NS_ + s0 + row) * DMEL + ko]);
      At[ko][row] = v.x; At[ko + 1][row] = v.y; At[ko + 2][row] = v.z; At[ko + 3][row] = v.w;
    }
    __syncthreads();
    float acc[4][4];
#pragma unroll
    for (int i = 0; i < 4; ++i)
#pragma unroll
      for (int j = 0; j < 4; ++j) acc[i][j] = 0.f;
#pragma unroll 8
    for (int kk = 0; kk < DMEL; ++kk) {
      float4 a = *reinterpret_cast<const float4*>(&At[kk][sy << 2]);
      float4 bb = *reinterpret_cast<const float4*>(&Bt[kk][tx << 2]);
      float av[4] = {a.x, a.y, a.z, a.w}, bv[4] = {bb.x, bb.y, bb.z, bb.w};
#pragma unroll
      for (int i = 0; i < 4; ++i)
#pragma unroll
        for (int j = 0; j < 4; ++j) acc[i][j] = fmaf(av[i], bv[j], acc[i][j]);
    }
    float nav[4];
#pragma unroll
    for (int i = 0; i < 4; ++i) nav[i] = na[b * NS_ + s0 + (sy << 2) + i];
#pragma unroll
    for (int j = 0; j < 4; ++j) {
      const bool tvalid = (t0 + (tx << 2) + j) < ml;
      float ov[4];
      float mNew = mACC[j];
#pragma unroll
      for (int i = 0; i < 4; ++i) {
        float d2 = (nav[i] + nbv[j]) - 2.0f * acc[i][j];
        float dist = sqrtf(fmaxf(d2, 1e-12f));
        bool valid = ((s0 + (sy << 2) + i) < sl) && tvalid;
        ov[i] = valid ? -dist : -1e9f;
        mNew = fmaxf(mNew, ov[i]);
      }
      float scale = expf(mACC[j] - mNew);
      float zadd = 0.f;
#pragma unroll
      for (int i = 0; i < 4; ++i) zadd += expf(ov[i] - mNew);
      zACC[j] = zACC[j] * scale + zadd;
      mACC[j] = mNew;
    }
  }
#pragma unroll
  for (int j = 0; j < 4; ++j) {
    redm[sy][(tx << 2) + j] = mACC[j];
    redz[sy][(tx << 2) + j] = zACC[j];
  }
  __syncthreads();
  if (tid < 64) {
    float M = NEGINF, Z = 0.f;
#pragma unroll
    for (int y = 0; y < 16; ++y) {
      float m = redm[y][tid], z = redz[y][tid];
      float Mn = fmaxf(M, m);
      Z = Z * expf(M - Mn) + z * expf(m - Mn);
      M = Mn;
    }
    marr[b * NT_ + t0 + tid] = M;
    rzarr[b * NT_ + t0 + tid] = 1.0f / Z;
  }
}

// ---------------- finalize: soft/rev f32 out + f32 val for DP ----------------
__global__ __launch_bounds__(256) void k_final3(
    const float* __restrict__ te, const float* __restrict__ me,
    const float* __restrict__ na, const float* __restrict__ nb,
    const float* __restrict__ marr, const float* __restrict__ rzarr,
    const int* __restrict__ src_len, const int* __restrict__ mel_len,
    float* __restrict__ val,
    float* __restrict__ soft, float* __restrict__ rev) {
  const int idx = blockIdx.x;
  const int tt = idx & 31;
  const int st = (idx >> 5) & 7;
  const int b = idx >> 8;
  const int s0 = st << 6, t0 = tt << 6;
  __shared__ float At[DMEL][68];
  __shared__ float Bt[DMEL][68];
  __shared__ float pl[64][65];
  const int tid = threadIdx.x;
  for (int f = tid; f < 64 * 20; f += 256) {
    int row = f / 20, ko = (f % 20) << 2;
    float4 v = *reinterpret_cast<const float4*>(
        &te[((size_t)b * NS_ + s0 + row) * DMEL + ko]);
    At[ko][row] = v.x; At[ko + 1][row] = v.y; At[ko + 2][row] = v.z; At[ko + 3][row] = v.w;
  }
  for (int f = tid; f < 64 * 20; f += 256) {
    int row = f / 20, ko = (f % 20) << 2;
    float4 v = *reinterpret_cast<const float4*>(
        &me[((size_t)b * NT_ + t0 + row) * DMEL + ko]);
    Bt[ko][row] = v.x; Bt[ko + 1][row] = v.y; Bt[ko + 2][row] = v.z; Bt[ko + 3][row] = v.w;
  }
  __syncthreads();
  const int tx = tid & 15, sy = tid >> 4;
  float acc[4][4];
#pragma unroll
  for (int i = 0; i < 4; ++i)
#pragma unroll
    for (int j = 0; j < 4; ++j) acc[i][j] = 0.f;
#pragma unroll 8
  for (int kk = 0; kk < DMEL; ++kk) {
    float4 a = *reinterpret_cast<const float4*>(&At[kk][sy << 2]);
    float4 bb = *reinterpret_cast<const float4*>(&Bt[kk][tx << 2]);
    float av[4] = {a.x, a.y, a.z, a.w}, bv[4] = {bb.x, bb.y, bb.z, bb.w};
#pragma unroll
    for (int i = 0; i < 4; ++i)
#pragma unroll
      for (int j = 0; j < 4; ++j) acc[i][j] = fmaf(av[i], bv[j], acc[i][j]);
  }
  const int sl = src_len[b], ml = mel_len[b];
  float nav[4], nbv[4];
#pragma unroll
  for (int i = 0; i < 4; ++i) nav[i] = na[b * NS_ + s0 + (sy << 2) + i];
#pragma unroll
  for (int j = 0; j < 4; ++j) nbv[j] = nb[b * NT_ + t0 + (tx << 2) + j];
#pragma unroll
  for (int j = 0; j < 4; ++j) {
    const int t = t0 + (tx << 2) + j;
    const bool tvalid = t < ml;
    const float mv = marr[b * NT_ + t];
    const float rzv = rzarr[b * NT_ + t];
    float pv[4];
#pragma unroll
    for (int i = 0; i < 4; ++i) {
      float d2 = (nav[i] + nbv[j]) - 2.0f * acc[i][j];
      float dist = sqrtf(fmaxf(d2, 1e-12f));
      bool valid = ((s0 + (sy << 2) + i) < sl) && tvalid;
      float ov = valid ? -dist : -1e9f;
      float p = tvalid ? expf(ov - mv) * rzv : 0.f;
      pv[i] = p;
      pl[(tx << 2) + j][(sy << 2) + i] = p;
    }
    float4 o = make_float4(pv[0], pv[1], pv[2], pv[3]);
    *reinterpret_cast<float4*>(&val[((size_t)b * NT_ + t) * NS_ + s0 + (sy << 2)]) = o;
  }
  __syncthreads();
  const int lane = tid & 63, w = tid >> 6;
#pragma unroll 4
  for (int i = 0; i < 16; ++i) {
    const int s_loc = (w << 4) + i;
    const int s = s0 + s_loc;
    float p = pl[lane][s_loc];
    size_t o = ((size_t)b * NS_ + s) * NT_ + t0 + lane;
    soft[o] = p;
    bool r = (s >= sl) || ((t0 + lane) >= ml);
    rev[o] = r ? 1.0f : 0.0f;
  }
}

// lane i <- lane i-1 via DPP wave_shr:1 (VALU, no LDS pipe). Lane 0 -> 0.
__device__ __forceinline__ float dp_shr1(float x) {
  int r = __builtin_amdgcn_update_dpp(0, __float_as_int(x), 0x138, 0xF, 0xF, true);
  return __int_as_float(r);
}

// RAW barrier: lgkmcnt(0) for cross-wave ds_write visibility, but NO vmcnt
// drain -- in-flight global loads stay outstanding across the barrier
// (the __syncthreads() vmcnt(0) drain was collapsing prefetch distance to 0).
__device__ __forceinline__ void dp_bar() {
  asm volatile("s_waitcnt lgkmcnt(0)" ::: "memory");
  __builtin_amdgcn_sched_barrier(0);
  __builtin_amdgcn_s_barrier();
}

// Consumer chunk body: 16 rows, 4-row register batches. MASKED = apply (s<=t).
#define DP_CHUNK(MASKED)                                                      \
  _Pragma("unroll")                                                           \
  for (int rb8 = 0; rb8 < 4; ++rb8) {                                         \
    float4 d0[4], d1[4];                                                      \
    _Pragma("unroll")                                                         \
    for (int rr = 0; rr < 4; ++rr) {                                          \
      const float* rp = rowbase + (((rb8 << 2) + rr) << 9);                   \
      d0[rr] = *reinterpret_cast<const float4*>(rp + (lane << 2));            \
      d1[rr] = *reinterpret_cast<const float4*>(rp + 256 + (lane << 2));      \
    }                                                                         \
    _Pragma("unroll")                                                         \
    for (int rr = 0; rr < 4; ++rr) {                                          \
      const int t = tbase + (rb8 << 2) + rr;                                  \
      float cc[8] = {d0[rr].x, d0[rr].y, d0[rr].z, d0[rr].w,                  \
                     d1[rr].x, d1[rr].y, d1[rr].z, d1[rr].w};                 \
      const int sh = t & 31;                                                  \
      if (t < ml) {                                                           \
        float up = dp_shr1(v[7]);                                             \
        float prev = (lane == 0) ? NEGINF : up;                               \
        _Pragma("unroll")                                                     \
        for (int j = 0; j < 8; ++j) {                                         \
          float cur = v[j];                                                   \
          bool keep = cur >= prev;                                            \
          float vm = fmaxf(cur, prev);                                        \
          float vn;                                                           \
          if (MASKED) {                                                       \
            int s = (lane << 3) + j;                                          \
            vn = (s <= t) ? vm + cc[j] : NEGINF;                              \
          } else {                                                            \
            vn = vm + cc[j];                                                  \
          }                                                                   \
          uint32_t bit = keep ? 1u : inv[j];                                  \
          bw[j] |= bit << sh;                                                 \
          v[j] = vn;                                                          \
          prev = cur;                                                         \
        }                                                                     \
      } else {                                                                \
        _Pragma("unroll")                                                     \
        for (int j = 0; j < 8; ++j) bw[j] |= 1u << sh;                        \
      }                                                                       \
    }                                                                         \
  }

// ---------------- DP forward scan: 1 consumer + 2 reg-staging producer waves ----
// De-interleave in the GLOBAL load addresses (rule 21): lane l loads floats
// [8l..8l+3] and [8l+4..8l+7]; writes LDS at float offsets 4l and 256+4l --
// byte-identical to the conflict-free consumer read pattern (measured 0).
// Loads for chunk c+2 issued at iter c, written at iter c+1. Raw s_barrier
// (dp_bar) keeps those loads IN FLIGHT across the barrier.
__global__ __launch_bounds__(192) void k_dp(const float* __restrict__ val,
                                            const int* __restrict__ src_len,
                                            const int* __restrict__ mel_len,
                                            uint32_t* __restrict__ dir) {
  __shared__ float buf[2][16][512];  // 64 KB double buffer
  const int b = blockIdx.x;
  const int wv = threadIdx.x >> 6;   // 0 = consumer, 1..2 = producers
  const int lane = threadIdx.x & 63;
  const float* base = val + (size_t)b * NT_ * NS_;
  const int sl = src_len[b];
  const int ml = mel_len[b];
  const float NEGINF = -__builtin_inff();

  // producer state: 8 rows per producer wave
  float4 ra[8], rb[8];
  const int r0 = (wv - 1) << 3;

  // consumer state
  float v[8];
  uint32_t bw[8], inv[8];
#pragma unroll
  for (int j = 0; j < 8; ++j) {
    v[j] = 0.0f;
    bw[j] = 0u;
    int s = (lane << 3) + j;
    inv[j] = (s < sl) ? 0u : 1u;
  }

  if (wv > 0) {
    // stage chunk 0 into buf0; preload chunk 1 into regs
#pragma unroll
    for (int rr = 0; rr < 8; ++rr) {
      const float* g = base + (size_t)(r0 + rr) * NS_;
      ra[rr] = *reinterpret_cast<const float4*>(g + (lane << 3));
      rb[rr] = *reinterpret_cast<const float4*>(g + (lane << 3) + 4);
    }
#pragma unroll
    for (int rr = 0; rr < 8; ++rr) {
      float* l = &buf[0][r0 + rr][0];
      *reinterpret_cast<float4*>(l + (lane << 2)) = ra[rr];
      *reinterpret_cast<float4*>(l + 256 + (lane << 2)) = rb[rr];
    }
#pragma unroll
    for (int rr = 0; rr < 8; ++rr) {
      const float* g = base + (size_t)(16 + r0 + rr) * NS_;
      ra[rr] = *reinterpret_cast<const float4*>(g + (lane << 3));
      rb[rr] = *reinterpret_cast<const float4*>(g + (lane << 3) + 4);
    }
  }
  dp_bar();

  for (int c = 0; c < 128; ++c) {
    if (wv > 0) {
      if (c + 1 < 128) {  // write chunk c+1 (regs loaded during iter c-1)
        const int nb = (c + 1) & 1;
#pragma unroll
        for (int rr = 0; rr < 8; ++rr) {
          float* l = &buf[nb][r0 + rr][0];
          *reinterpret_cast<float4*>(l + (lane << 2)) = ra[rr];
          *reinterpret_cast<float4*>(l + 256 + (lane << 2)) = rb[rr];
        }
      }
      if (c + 2 < 128) {  // issue loads for chunk c+2 (stay in flight past barrier)
        const float* cb = base + ((size_t)(c + 2) * 16 + r0) * NS_;
#pragma unroll
        for (int rr = 0; rr < 8; ++rr) {
          const float* g = cb + (size_t)rr * NS_;
          ra[rr] = *reinterpret_cast<const float4*>(g + (lane << 3));
          rb[rr] = *reinterpret_cast<const float4*>(g + (lane << 3) + 4);
        }
      }
    } else {
      const float* rowbase = &buf[c & 1][0][0];
      const int tbase = c << 4;
      if (c < 32) {
        DP_CHUNK(true)
      } else {
        DP_CHUNK(false)
      }
      if (c & 1) {  // 32 rows accumulated -> store direction words
        const int c32 = c >> 1;
#pragma unroll
        for (int j = 0; j < 8; ++j) {
          dir[((size_t)(b * NS_) + (lane << 3) + j) * 64 + c32] = bw[j];
          bw[j] = 0u;
        }
      }
    }
    dp_bar();
  }
}

// ---------------- backtrack (two half-T phases) ----------------
__global__ __launch_bounds__(256) void k_backtrack(
    const uint32_t* __restrict__ dir, const int* __restrict__ src_len,
    const int* __restrict__ mel_len, float* __restrict__ hard,
    int* __restrict__ idxio, int phase) {
  __shared__ uint32_t dl[NS_ * 32];
  const int b = blockIdx.x, tid = threadIdx.x;
  const uint32_t* db = dir + (size_t)b * NS_ * 64;
  const int woff = phase ? 0 : 32;
  for (int f = tid; f < 4096; f += 256) {
    int s = f >> 3;
    int wo = (f & 7) << 2;
    *reinterpret_cast<uint4*>(&dl[s * 32 + wo]) =
        *reinterpret_cast<const uint4*>(&db[s * 64 + woff + wo]);
  }
  __syncthreads();
  if (tid == 0) {
    const int ml = mel_len[b];
    int idx = phase ? idxio[b] : (src_len[b] - 1);
    if (idx < 0) idx = 0;
    if (idx > NS_ - 1) idx = NS_ - 1;
    const int thi = phase ? 1023 : 2047;
    const int tlo = phase ? 0 : 1024;
    int cw = -1, ci = -1;
    uint32_t w = 0;
    for (int t = thi; t >= tlo; --t) {
      int wi = t >> 5;
      if (wi != cw || idx != ci) {
        w = dl[idx * 32 + (wi - woff)];
        cw = wi;
        ci = idx;
      }
      if (t < ml) hard[((size_t)(b * NS_) + idx) * NT_ + t] = 1.0f;
      int step = (int)((w >> (t & 31)) & 1) - 1;
      idx += step;
      if (idx < 0) idx = 0;
    }
    if (!phase) idxio[b] = idx;
  }
}

// ---------------- host launch ----------------
extern "C" void kernel_launch(void* const* d_in, const int* in_sizes, int n_in,
                              void* d_out, int out_size, void* d_ws, size_t ws_size,
                              hipStream_t stream) {
  if (n_in != 17) return;
  if (ws_size < FULL_NEED) return;

  const void* text = d_in[0];
  const void* mel = d_in[1];
  const int* src_len = (const int*)d_in[2];
  const int* mel_len = (const int*)d_in[3];
  const void* tw1 = d_in[7];
  const void* tb1 = d_in[8];
  const void* tw2 = d_in[9];
  const void* tb2 = d_in[10];
  const void* mw1 = d_in[11];
  const void* mb1 = d_in[12];
  const void* mw2 = d_in[13];
  const void* mb2 = d_in[14];
  const void* mw3 = d_in[15];
  const void* mb3 = d_in[16];

  char* w8 = (char*)d_ws;
  float* mel_f32 = (float*)(w8 + 0);
  float* melh1 = (float*)(w8 + 20971520ull);
  float* mh2 = (float*)(w8 + 62914560ull);
  float* text_f32 = (float*)(w8 + 83886080ull);
  float* texth1 = (float*)(w8 + 100663296ull);
  float* val = (float*)(w8 + 0);

  float* te = (float*)(w8 + P + PO_TE);
  float* me = (float*)(w8 + P + PO_ME);
  float* na = (float*)(w8 + P + PO_NA);
  float* nb = (float*)(w8 + P + PO_NB);
  float* marr = (float*)(w8 + P + PO_M);
  float* rzarr = (float*)(w8 + P + PO_RZ);
  float* wt1 = (float*)(w8 + P + PO_W1);
  float* wt2 = (float*)(w8 + P + PO_W2);
  float* wt3 = (float*)(w8 + P + PO_W3);
  float* wt4 = (float*)(w8 + P + PO_W4);
  float* wt5 = (float*)(w8 + P + PO_W5);
  float* biasb = (float*)(w8 + P + PO_BIAS);
  uint32_t* dir = (uint32_t*)(w8 + P + PO_DIR);
  int* idxio = (int*)(w8 + P + PO_IDX);
  int* flag = (int*)(w8 + P + PO_FLAG);

  // outputs are float32
  float* soft = (float*)d_out;
  float* hard = soft + (size_t)NB_ * NS_ * NT_;
  float* rev = soft + 2 * (size_t)NB_ * NS_ * NT_;

  // dtype detect + converts
  k_detect<<<1, 256, 0, stream>>>((const uint32_t*)text, flag);
  k_cvt<<<(NB_ * NS_ * 256 + 255) / 256, 256, 0, stream>>>(text, text_f32, NB_ * NS_ * 256, flag);
  k_cvt<<<(NB_ * NT_ * 80 + 255) / 256, 256, 0, stream>>>(mel, mel_f32, NB_ * NT_ * 80, flag);
  k_cvt<<<2, 256, 0, stream>>>(tb1, biasb + BO_T1, 512, flag);
  k_cvt<<<1, 256, 0, stream>>>(tb2, biasb + BO_T2, 80, flag);
  k_cvt<<<1, 256, 0, stream>>>(mb1, biasb + BO_M1, 160, flag);
  k_cvt<<<1, 256, 0, stream>>>(mb2, biasb + BO_M2, 80, flag);
  k_cvt<<<1, 256, 0, stream>>>(mb3, biasb + BO_M3, 80, flag);

  // weight transposes
  k_wtrans<<<(512 * 256 * 3 + 255) / 256, 256, 0, stream>>>(tw1, wt1, 512, 256, 3, 512 * 256 * 3, flag);
  k_wtrans<<<(80 * 512 + 255) / 256, 256, 0, stream>>>(tw2, wt2, 80, 512, 1, 80 * 512, flag);
  k_wtrans<<<(160 * 80 * 3 + 255) / 256, 256, 0, stream>>>(mw1, wt3, 160, 80, 3, 160 * 80 * 3, flag);
  k_wtrans<<<(80 * 160 * 3 + 255) / 256, 256, 0, stream>>>(mw2, wt4, 80, 160, 3, 80 * 160 * 3, flag);
  k_wtrans<<<(80 * 80 + 255) / 256, 256, 0, stream>>>(mw3, wt5, 80, 80, 1, 80 * 80, flag);

  // encoders (pure f32)
  k_conv<80, 3, 160, 80, 5, 16, 11, 2, false><<<512 * 2, 256, 0, stream>>>(mel_f32, wt3, biasb + BO_M1, melh1, nullptr);
  k_conv<160, 3, 80, 80, 5, 32, 11, 2, false><<<512 * 1, 256, 0, stream>>>(melh1, wt4, biasb + BO_M2, mh2, nullptr);
  k_conv<80, 1, 80, 80, 5, 16, 11, 0, true><<<512 * 1, 256, 0, stream>>>(mh2, wt5, biasb + BO_M3, me, mel_len);
  k_conv<256, 3, 512, 128, 8, 32, 9, 1, false><<<128 * 4, 256, 0, stream>>>(text_f32, wt1, biasb + BO_T1, texth1, nullptr);
  k_conv<512, 1, 80, 80, 5, 32, 9, 0, true><<<128 * 1, 256, 0, stream>>>(texth1, wt2, biasb + BO_T2, te, src_len);

  // norms
  k_norms<<<(NB_ * NS_ * 4) / 256, 256, 0, stream>>>(te, na, NB_ * NS_);
  k_norms<<<(NB_ * NT_ * 4) / 256, 256, 0, stream>>>(me, nb, NB_ * NT_);

  // hard_A zero EARLY so its 128MB write traffic doesn't evict val from L3
  hipMemsetAsync(hard, 0, (size_t)NB_ * NS_ * NT_ * 4, stream);

  // softmax stats + finalize
  k_stats2<<<NB_ * 32, 256, 0, stream>>>(te, me, na, nb, src_len, mel_len, marr, rzarr);
  k_final3<<<NB_ * 8 * 32, 256, 0, stream>>>(te, me, na, nb, marr, rzarr, src_len, mel_len,
                                             val, soft, rev);

  // DP + backtrack
  k_dp<<<NB_, 192, 0, stream>>>(val, src_len, mel_len, dir);
  k_backtrack<<<NB_, 256, 0, stream>>>(dir, src_len, mel_len, hard, idxio, 0);
  k_backtrack<<<NB_, 256, 0, stream>>>(dir, src_len, mel_len, hard, idxio, 1);
}

// Round 14
// 1330.132 us; speedup vs baseline: 1.2556x; 1.0079x over previous
//
#include <hip/hip_runtime.h>
#include <hip/hip_bf16.h>
#include <cstdint>

// Problem constants
constexpr int NB_ = 32;     // batch
constexpr int NS_ = 512;    // text length S
constexpr int NT_ = 2048;   // mel length T
constexpr int DMEL = 80;    // embedding dim

// ---------------- workspace layout ----------------
constexpr size_t P = 134217728ull;  // persistent block base
constexpr size_t PO_TE   = 0ull;
constexpr size_t PO_ME   = 5242880ull;
constexpr size_t PO_NA   = 26214400ull;
constexpr size_t PO_NB   = 26279936ull;
constexpr size_t PO_M    = 26542080ull;
constexpr size_t PO_RZ   = 26804224ull;
constexpr size_t PO_W1   = 27066368ull;
constexpr size_t PO_W2   = 28639232ull;
constexpr size_t PO_W3   = 28803072ull;
constexpr size_t PO_W4   = 28956672ull;
constexpr size_t PO_W5   = 29110272ull;
constexpr size_t PO_BIAS = 29135872ull;
constexpr size_t PO_DIR  = 29139968ull;
constexpr size_t PO_IDX  = 33334272ull;
constexpr size_t PO_FLAG = 33334400ull;
constexpr size_t FULL_NEED = P + 33334528ull;

constexpr int BO_T1 = 0, BO_T2 = 512, BO_M1 = 592, BO_M2 = 752, BO_M3 = 832;

// ---------------- dtype detect: bf16 vs f32 probe on text ----------------
__global__ void k_detect(const uint32_t* __restrict__ w, int* __restrict__ flag) {
  __shared__ int red[256];
  const int tid = threadIdx.x;
  int cnt = 0;
  for (int i = tid; i < 4096; i += 256) {
    uint32_t e = (w[i] >> 7) & 0xFFu;
    cnt += (e >= 119u && e <= 129u) ? 1 : 0;
  }
  red[tid] = cnt;
  __syncthreads();
  for (int s = 128; s > 0; s >>= 1) {
    if (tid < s) red[tid] += red[tid + s];
    __syncthreads();
  }
  if (tid == 0) *flag = (red[0] > 2048) ? 1 : 0;
}

// ---------------- flag-branched convert to f32 ----------------
__global__ void k_cvt(const void* __restrict__ in, float* __restrict__ out, int n,
                      const int* __restrict__ flag) {
  const int i = blockIdx.x * 256 + threadIdx.x;
  if (i >= n) return;
  if (*flag) {
    uint16_t u = ((const uint16_t*)in)[i];
    out[i] = __uint_as_float((uint32_t)u << 16);
  } else {
    out[i] = ((const float*)in)[i];
  }
}

// ---------------- weight transpose ----------------
__global__ void k_wtrans(const void* __restrict__ w, float* __restrict__ wT,
                         int CO, int CI, int KW, int total, const int* __restrict__ flag) {
  int id = blockIdx.x * 256 + threadIdx.x;
  if (id >= total) return;
  int co = id % CO;
  int rest = id / CO;
  int ci = rest % CI;
  int tap = rest / CI;
  int src = (co * CI + ci) * KW + tap;
  if (*flag) {
    uint16_t u = ((const uint16_t*)w)[src];
    wT[id] = __uint_as_float((uint32_t)u << 16);
  } else {
    wT[id] = ((const float*)w)[src];
  }
}

// ---------------- conv1d as implicit GEMM (pure f32) ----------------
template <int CIN, int KW, int COUT, int NTILE, int NR, int KC, int LOG2L, int ACT, bool MASK>
__global__ __launch_bounds__(256) void k_conv(const float* __restrict__ x,
                                              const float* __restrict__ wT,
                                              const float* __restrict__ bias,
                                              float* __restrict__ y,
                                              const int* __restrict__ lenArr) {
  constexpr int L = 1 << LOG2L;
  constexpr int PAD = (KW - 1) / 2;
  constexpr int MT = 128;
  constexpr int APAD = 132;
  constexpr int BPAD = NTILE + 4;
  __shared__ float As[KC][APAD];
  __shared__ float Bs[KC][BPAD];

  const int tid = threadIdx.x;
  const int tx = tid & 15;
  const int ty = tid >> 4;
  constexpr int NBLK = COUT / NTILE;
  const int m0 = (blockIdx.x / NBLK) * MT;
  const int n0 = (blockIdx.x % NBLK) * NTILE;

  float acc[8][NR];
#pragma unroll
  for (int i = 0; i < 8; ++i)
#pragma unroll
    for (int j = 0; j < NR; ++j) acc[i][j] = 0.f;

  for (int tap = 0; tap < KW; ++tap) {
    for (int k0 = 0; k0 < CIN; k0 += KC) {
      __syncthreads();
      constexpr int AF4 = MT * KC / 4;
      constexpr int F4R = KC / 4;
      for (int f = tid; f < AF4; f += 256) {
        int row = f / F4R;
        int ko = (f % F4R) * 4;
        int r = m0 + row;
        int b = r >> LOG2L;
        int pos = (r & (L - 1)) + tap - PAD;
        float4 v = make_float4(0.f, 0.f, 0.f, 0.f);
        if (pos >= 0 && pos < L)
          v = *reinterpret_cast<const float4*>(
              &x[((size_t)(b << LOG2L) + pos) * CIN + k0 + ko]);
        As[ko + 0][row] = v.x;
        As[ko + 1][row] = v.y;
        As[ko + 2][row] = v.z;
        As[ko + 3][row] = v.w;
      }
      constexpr int BF4 = KC * NTILE / 4;
      constexpr int BF4R = NTILE / 4;
      for (int f = tid; f < BF4; f += 256) {
        int kk = f / BF4R;
        int no = (f % BF4R) * 4;
        float4 v = *reinterpret_cast<const float4*>(
            &wT[((size_t)(tap * CIN + k0 + kk)) * COUT + n0 + no]);
        *reinterpret_cast<float4*>(&Bs[kk][no]) = v;
      }
      __syncthreads();
#pragma unroll 8
      for (int kk = 0; kk < KC; ++kk) {
        float4 a0 = *reinterpret_cast<const float4*>(&As[kk][ty * 8]);
        float4 a1 = *reinterpret_cast<const float4*>(&As[kk][ty * 8 + 4]);
        float av[8] = {a0.x, a0.y, a0.z, a0.w, a1.x, a1.y, a1.z, a1.w};
        float bv[NR];
#pragma unroll
        for (int j = 0; j < NR; ++j) bv[j] = Bs[kk][tx * NR + j];
#pragma unroll
        for (int i = 0; i < 8; ++i)
#pragma unroll
          for (int j = 0; j < NR; ++j) acc[i][j] = fmaf(av[i], bv[j], acc[i][j]);
      }
    }
  }
#pragma unroll
  for (int i = 0; i < 8; ++i) {
    int r = m0 + ty * 8 + i;
    int b = r >> LOG2L;
    int pos = r & (L - 1);
    bool zero = MASK && (pos >= lenArr[b]);
#pragma unroll
    for (int j = 0; j < NR; ++j) {
      int c = n0 + tx * NR + j;
      float v = acc[i][j] + bias[c];
      if (ACT == 1) v = fmaxf(v, 0.f);
      if (ACT == 2) v = (v >= 0.f) ? v : 0.01f * v;
      if (zero) v = 0.f;
      y[(size_t)r * COUT + c] = v;
    }
  }
}

// ---------------- row squared-norms ----------------
__global__ void k_norms(const float* __restrict__ e, float* __restrict__ out, int rows) {
  int tid = blockIdx.x * 256 + threadIdx.x;
  int row = tid >> 2, sub = tid & 3;
  if (row >= rows) return;
  const float* p = e + (size_t)row * DMEL;
  float s = 0.f;
#pragma unroll
  for (int j = 0; j < 5; ++j) {
    float4 v = *reinterpret_cast<const float4*>(&p[(sub + 4 * j) * 4]);
    s = fmaf(v.x, v.x, fmaf(v.y, v.y, fmaf(v.z, v.z, fmaf(v.w, v.w, s))));
  }
  s += __shfl_xor(s, 1);
  s += __shfl_xor(s, 2);
  if (sub == 0) out[row] = s;
}

// ---------------- softmax stats by recomputation ----------------
__global__ __launch_bounds__(256) void k_stats2(
    const float* __restrict__ te, const float* __restrict__ me,
    const float* __restrict__ na, const float* __restrict__ nb,
    const int* __restrict__ src_len, const int* __restrict__ mel_len,
    float* __restrict__ marr, float* __restrict__ rzarr) {
  const int b = blockIdx.x >> 5;
  const int t0 = (blockIdx.x & 31) << 6;
  __shared__ float Bt[DMEL][68];
  __shared__ float At[DMEL][68];
  __shared__ float redm[16][64];
  __shared__ float redz[16][64];
  const int tid = threadIdx.x;
  for (int f = tid; f < 64 * 20; f += 256) {
    int row = f / 20, ko = (f % 20) << 2;
    float4 v = *reinterpret_cast<const float4*>(
        &me[((size_t)b * NT_ + t0 + row) * DMEL + ko]);
    Bt[ko][row] = v.x; Bt[ko + 1][row] = v.y; Bt[ko + 2][row] = v.z; Bt[ko + 3][row] = v.w;
  }
  const int tx = tid & 15, sy = tid >> 4;
  const int sl = src_len[b], ml = mel_len[b];
  const float NEGINF = -__builtin_inff();
  float nbv[4], mACC[4], zACC[4];
#pragma unroll
  for (int j = 0; j < 4; ++j) {
    nbv[j] = nb[b * NT_ + t0 + (tx << 2) + j];
    mACC[j] = NEGINF;
    zACC[j] = 0.f;
  }
  for (int c = 0; c < 8; ++c) {
    const int s0 = c << 6;
    __syncthreads();
    for (int f = tid; f < 64 * 20; f += 256) {
      int row = f / 20, ko = (f % 20) << 2;
      float4 v = *reinterpret_cast<const float4*>(
          &te[((size_t)b * NS_ + s0 + row) * DMEL + ko]);
      At[ko][row] = v.x; At[ko + 1][row] = v.y; At[ko + 2][row] = v.z; At[ko + 3][row] = v.w;
    }
    __syncthreads();
    float acc[4][4];
#pragma unroll
    for (int i = 0; i < 4; ++i)
#pragma unroll
      for (int j = 0; j < 4; ++j) acc[i][j] = 0.f;
#pragma unroll 8
    for (int kk = 0; kk < DMEL; ++kk) {
      float4 a = *reinterpret_cast<const float4*>(&At[kk][sy << 2]);
      float4 bb = *reinterpret_cast<const float4*>(&Bt[kk][tx << 2]);
      float av[4] = {a.x, a.y, a.z, a.w}, bv[4] = {bb.x, bb.y, bb.z, bb.w};
#pragma unroll
      for (int i = 0; i < 4; ++i)
#pragma unroll
        for (int j = 0; j < 4; ++j) acc[i][j] = fmaf(av[i], bv[j], acc[i][j]);
    }
    float nav[4];
#pragma unroll
    for (int i = 0; i < 4; ++i) nav[i] = na[b * NS_ + s0 + (sy << 2) + i];
#pragma unroll
    for (int j = 0; j < 4; ++j) {
      const bool tvalid = (t0 + (tx << 2) + j) < ml;
      float ov[4];
      float mNew = mACC[j];
#pragma unroll
      for (int i = 0; i < 4; ++i) {
        float d2 = (nav[i] + nbv[j]) - 2.0f * acc[i][j];
        float dist = sqrtf(fmaxf(d2, 1e-12f));
        bool valid = ((s0 + (sy << 2) + i) < sl) && tvalid;
        ov[i] = valid ? -dist : -1e9f;
        mNew = fmaxf(mNew, ov[i]);
      }
      float scale = expf(mACC[j] - mNew);
      float zadd = 0.f;
#pragma unroll
      for (int i = 0; i < 4; ++i) zadd += expf(ov[i] - mNew);
      zACC[j] = zACC[j] * scale + zadd;
      mACC[j] = mNew;
    }
  }
#pragma unroll
  for (int j = 0; j < 4; ++j) {
    redm[sy][(tx << 2) + j] = mACC[j];
    redz[sy][(tx << 2) + j] = zACC[j];
  }
  __syncthreads();
  if (tid < 64) {
    float M = NEGINF, Z = 0.f;
#pragma unroll
    for (int y = 0; y < 16; ++y) {
      float m = redm[y][tid], z = redz[y][tid];
      float Mn = fmaxf(M, m);
      Z = Z * expf(M - Mn) + z * expf(m - Mn);
      M = Mn;
    }
    marr[b * NT_ + t0 + tid] = M;
    rzarr[b * NT_ + t0 + tid] = 1.0f / Z;
  }
}

// ---------------- finalize: soft/rev f32 out + f32 val for DP ----------------
// Thread-tile roles: sy = tid&15 (s dim), tx = tid>>4 (t dim) -- lane varies
// in s, so the val float4 store is 4x256B contiguous segments per wave
// (was 64x scattered 16B at 2KB stride with the old mapping).
__global__ __launch_bounds__(256) void k_final3(
    const float* __restrict__ te, const float* __restrict__ me,
    const float* __restrict__ na, const float* __restrict__ nb,
    const float* __restrict__ marr, const float* __restrict__ rzarr,
    const int* __restrict__ src_len, const int* __restrict__ mel_len,
    float* __restrict__ val,
    float* __restrict__ soft, float* __restrict__ rev) {
  const int idx = blockIdx.x;
  const int tt = idx & 31;
  const int st = (idx >> 5) & 7;
  const int b = idx >> 8;
  const int s0 = st << 6, t0 = tt << 6;
  __shared__ float At[DMEL][68];
  __shared__ float Bt[DMEL][68];
  __shared__ float pl[64][65];
  const int tid = threadIdx.x;
  for (int f = tid; f < 64 * 20; f += 256) {
    int row = f / 20, ko = (f % 20) << 2;
    float4 v = *reinterpret_cast<const float4*>(
        &te[((size_t)b * NS_ + s0 + row) * DMEL + ko]);
    At[ko][row] = v.x; At[ko + 1][row] = v.y; At[ko + 2][row] = v.z; At[ko + 3][row] = v.w;
  }
  for (int f = tid; f < 64 * 20; f += 256) {
    int row = f / 20, ko = (f % 20) << 2;
    float4 v = *reinterpret_cast<const float4*>(
        &me[((size_t)b * NT_ + t0 + row) * DMEL + ko]);
    Bt[ko][row] = v.x; Bt[ko + 1][row] = v.y; Bt[ko + 2][row] = v.z; Bt[ko + 3][row] = v.w;
  }
  __syncthreads();
  const int sy = tid & 15, tx = tid >> 4;  // SWAPPED: lane varies in s
  float acc[4][4];
#pragma unroll
  for (int i = 0; i < 4; ++i)
#pragma unroll
    for (int j = 0; j < 4; ++j) acc[i][j] = 0.f;
#pragma unroll 8
  for (int kk = 0; kk < DMEL; ++kk) {
    float4 a = *reinterpret_cast<const float4*>(&At[kk][sy << 2]);
    float4 bb = *reinterpret_cast<const float4*>(&Bt[kk][tx << 2]);
    float av[4] = {a.x, a.y, a.z, a.w}, bv[4] = {bb.x, bb.y, bb.z, bb.w};
#pragma unroll
    for (int i = 0; i < 4; ++i)
#pragma unroll
      for (int j = 0; j < 4; ++j) acc[i][j] = fmaf(av[i], bv[j], acc[i][j]);
  }
  const int sl = src_len[b], ml = mel_len[b];
  float nav[4], nbv[4];
#pragma unroll
  for (int i = 0; i < 4; ++i) nav[i] = na[b * NS_ + s0 + (sy << 2) + i];
#pragma unroll
  for (int j = 0; j < 4; ++j) nbv[j] = nb[b * NT_ + t0 + (tx << 2) + j];
#pragma unroll
  for (int j = 0; j < 4; ++j) {
    const int t = t0 + (tx << 2) + j;
    const bool tvalid = t < ml;
    const float mv = marr[b * NT_ + t];
    const float rzv = rzarr[b * NT_ + t];
    float pv[4];
#pragma unroll
    for (int i = 0; i < 4; ++i) {
      float d2 = (nav[i] + nbv[j]) - 2.0f * acc[i][j];
      float dist = sqrtf(fmaxf(d2, 1e-12f));
      bool valid = ((s0 + (sy << 2) + i) < sl) && tvalid;
      float ov = valid ? -dist : -1e9f;
      float p = tvalid ? expf(ov - mv) * rzv : 0.f;
      pv[i] = p;
      pl[(tx << 2) + j][(sy << 2) + i] = p;
    }
    float4 o = make_float4(pv[0], pv[1], pv[2], pv[3]);
    *reinterpret_cast<float4*>(&val[((size_t)b * NT_ + t) * NS_ + s0 + (sy << 2)]) = o;
  }
  __syncthreads();
  const int lane = tid & 63, w = tid >> 6;
#pragma unroll 4
  for (int i = 0; i < 16; ++i) {
    const int s_loc = (w << 4) + i;
    const int s = s0 + s_loc;
    float p = pl[lane][s_loc];
    size_t o = ((size_t)b * NS_ + s) * NT_ + t0 + lane;
    soft[o] = p;
    bool r = (s >= sl) || ((t0 + lane) >= ml);
    rev[o] = r ? 1.0f : 0.0f;
  }
}

// lane i <- lane i-1 via DPP wave_shr:1 (VALU, no LDS pipe). Lane 0 -> 0.
__device__ __forceinline__ float dp_shr1(float x) {
  int r = __builtin_amdgcn_update_dpp(0, __float_as_int(x), 0x138, 0xF, 0xF, true);
  return __int_as_float(r);
}

// RAW barrier: lgkmcnt(0) for cross-wave ds_write visibility, no vmcnt drain.
__device__ __forceinline__ void dp_bar() {
  asm volatile("s_waitcnt lgkmcnt(0)" ::: "memory");
  __builtin_amdgcn_sched_barrier(0);
  __builtin_amdgcn_s_barrier();
}

// Consumer chunk body: 16 rows, 4-row register batches. MASKED = apply (s<=t).
#define DP_CHUNK(MASKED)                                                      \
  _Pragma("unroll")                                                           \
  for (int rb8 = 0; rb8 < 4; ++rb8) {                                         \
    float4 d0[4], d1[4];                                                      \
    _Pragma("unroll")                                                         \
    for (int rr = 0; rr < 4; ++rr) {                                          \
      const float* rp = rowbase + (((rb8 << 2) + rr) << 9);                   \
      d0[rr] = *reinterpret_cast<const float4*>(rp + (lane << 2));            \
      d1[rr] = *reinterpret_cast<const float4*>(rp + 256 + (lane << 2));      \
    }                                                                         \
    _Pragma("unroll")                                                         \
    for (int rr = 0; rr < 4; ++rr) {                                          \
      const int t = tbase + (rb8 << 2) + rr;                                  \
      float cc[8] = {d0[rr].x, d0[rr].y, d0[rr].z, d0[rr].w,                  \
                     d1[rr].x, d1[rr].y, d1[rr].z, d1[rr].w};                 \
      const int sh = t & 31;                                                  \
      if (t < ml) {                                                           \
        float up = dp_shr1(v[7]);                                             \
        float prev = (lane == 0) ? NEGINF : up;                               \
        _Pragma("unroll")                                                     \
        for (int j = 0; j < 8; ++j) {                                         \
          float cur = v[j];                                                   \
          bool keep = cur >= prev;                                            \
          float vm = fmaxf(cur, prev);                                        \
          float vn;                                                           \
          if (MASKED) {                                                       \
            int s = (lane << 3) + j;                                          \
            vn = (s <= t) ? vm + cc[j] : NEGINF;                              \
          } else {                                                            \
            vn = vm + cc[j];                                                  \
          }                                                                   \
          uint32_t bit = keep ? 1u : inv[j];                                  \
          bw[j] |= bit << sh;                                                 \
          v[j] = vn;                                                          \
          prev = cur;                                                         \
        }                                                                     \
      } else {                                                                \
        _Pragma("unroll")                                                     \
        for (int j = 0; j < 8; ++j) bw[j] |= 1u << sh;                        \
      }                                                                       \
    }                                                                         \
  }

// ---------------- DP forward scan: 1 consumer + 2 reg-staging producer waves ----
// Scan capped at C_act = ceil(ml/32)*2 chunks (wave-uniform). Rows beyond get
// constant all-1 direction words written in bulk (masked region: direction=1).
__global__ __launch_bounds__(192) void k_dp(const float* __restrict__ val,
                                            const int* __restrict__ src_len,
                                            const int* __restrict__ mel_len,
                                            uint32_t* __restrict__ dir) {
  __shared__ float buf[2][16][512];  // 64 KB double buffer
  const int b = blockIdx.x;
  const int wv = threadIdx.x >> 6;   // 0 = consumer, 1..2 = producers
  const int lane = threadIdx.x & 63;
  const float* base = val + (size_t)b * NT_ * NS_;
  const int sl = src_len[b];
  const int ml = mel_len[b];
  const float NEGINF = -__builtin_inff();
  // chunks actually scanned (even count; >= ml rows, uniform across waves)
  int ca = ((ml + 31) >> 5) << 1;
  const int C_act = ca > 128 ? 128 : ca;

  // producer state: 8 rows per producer wave
  float4 ra[8], rb[8];
  const int r0 = (wv - 1) << 3;

  // consumer state
  float v[8];
  uint32_t bw[8], inv[8];
#pragma unroll
  for (int j = 0; j < 8; ++j) {
    v[j] = 0.0f;
    bw[j] = 0u;
    int s = (lane << 3) + j;
    inv[j] = (s < sl) ? 0u : 1u;
  }

  if (wv > 0) {
    // stage chunk 0 into buf0; preload chunk 1 into regs
#pragma unroll
    for (int rr = 0; rr < 8; ++rr) {
      const float* g = base + (size_t)(r0 + rr) * NS_;
      ra[rr] = *reinterpret_cast<const float4*>(g + (lane << 3));
      rb[rr] = *reinterpret_cast<const float4*>(g + (lane << 3) + 4);
    }
#pragma unroll
    for (int rr = 0; rr < 8; ++rr) {
      float* l = &buf[0][r0 + rr][0];
      *reinterpret_cast<float4*>(l + (lane << 2)) = ra[rr];
      *reinterpret_cast<float4*>(l + 256 + (lane << 2)) = rb[rr];
    }
#pragma unroll
    for (int rr = 0; rr < 8; ++rr) {
      const float* g = base + (size_t)(16 + r0 + rr) * NS_;
      ra[rr] = *reinterpret_cast<const float4*>(g + (lane << 3));
      rb[rr] = *reinterpret_cast<const float4*>(g + (lane << 3) + 4);
    }
  }
  dp_bar();

  for (int c = 0; c < C_act; ++c) {
    if (wv > 0) {
      if (c + 1 < C_act) {  // write chunk c+1 (regs loaded during iter c-1)
        const int nb = (c + 1) & 1;
#pragma unroll
        for (int rr = 0; rr < 8; ++rr) {
          float* l = &buf[nb][r0 + rr][0];
          *reinterpret_cast<float4*>(l + (lane << 2)) = ra[rr];
          *reinterpret_cast<float4*>(l + 256 + (lane << 2)) = rb[rr];
        }
      }
      if (c + 2 < C_act) {  // issue loads for chunk c+2 (stay in flight)
        const float* cb = base + ((size_t)(c + 2) * 16 + r0) * NS_;
#pragma unroll
        for (int rr = 0; rr < 8; ++rr) {
          const float* g = cb + (size_t)rr * NS_;
          ra[rr] = *reinterpret_cast<const float4*>(g + (lane << 3));
          rb[rr] = *reinterpret_cast<const float4*>(g + (lane << 3) + 4);
        }
      }
    } else {
      const float* rowbase = &buf[c & 1][0][0];
      const int tbase = c << 4;
      if (c < 32) {
        DP_CHUNK(true)
      } else {
        DP_CHUNK(false)
      }
      if (c & 1) {  // 32 rows accumulated -> store direction words
        const int c32 = c >> 1;
#pragma unroll
        for (int j = 0; j < 8; ++j) {
          dir[((size_t)(b * NS_) + (lane << 3) + j) * 64 + c32] = bw[j];
          bw[j] = 0u;
        }
      }
    }
    dp_bar();
  }
  // tail: all rows t >= C_act*16 >= ml are masked -> direction = 1
  if (wv == 0) {
    for (int c32 = C_act >> 1; c32 < 64; ++c32) {
#pragma unroll
      for (int j = 0; j < 8; ++j)
        dir[((size_t)(b * NS_) + (lane << 3) + j) * 64 + c32] = 0xFFFFFFFFu;
    }
  }
}

// ---------------- backtrack (two half-T phases) ----------------
__global__ __launch_bounds__(256) void k_backtrack(
    const uint32_t* __restrict__ dir, const int* __restrict__ src_len,
    const int* __restrict__ mel_len, float* __restrict__ hard,
    int* __restrict__ idxio, int phase) {
  __shared__ uint32_t dl[NS_ * 32];
  const int b = blockIdx.x, tid = threadIdx.x;
  const uint32_t* db = dir + (size_t)b * NS_ * 64;
  const int woff = phase ? 0 : 32;
  for (int f = tid; f < 4096; f += 256) {
    int s = f >> 3;
    int wo = (f & 7) << 2;
    *reinterpret_cast<uint4*>(&dl[s * 32 + wo]) =
        *reinterpret_cast<const uint4*>(&db[s * 64 + woff + wo]);
  }
  __syncthreads();
  if (tid == 0) {
    const int ml = mel_len[b];
    int idx = phase ? idxio[b] : (src_len[b] - 1);
    if (idx < 0) idx = 0;
    if (idx > NS_ - 1) idx = NS_ - 1;
    const int thi = phase ? 1023 : 2047;
    const int tlo = phase ? 0 : 1024;
    int cw = -1, ci = -1;
    uint32_t w = 0;
    for (int t = thi; t >= tlo; --t) {
      int wi = t >> 5;
      if (wi != cw || idx != ci) {
        w = dl[idx * 32 + (wi - woff)];
        cw = wi;
        ci = idx;
      }
      if (t < ml) hard[((size_t)(b * NS_) + idx) * NT_ + t] = 1.0f;
      int step = (int)((w >> (t & 31)) & 1) - 1;
      idx += step;
      if (idx < 0) idx = 0;
    }
    if (!phase) idxio[b] = idx;
  }
}

// ---------------- host launch ----------------
extern "C" void kernel_launch(void* const* d_in, const int* in_sizes, int n_in,
                              void* d_out, int out_size, void* d_ws, size_t ws_size,
                              hipStream_t stream) {
  if (n_in != 17) return;
  if (ws_size < FULL_NEED) return;

  const void* text = d_in[0];
  const void* mel = d_in[1];
  const int* src_len = (const int*)d_in[2];
  const int* mel_len = (const int*)d_in[3];
  const void* tw1 = d_in[7];
  const void* tb1 = d_in[8];
  const void* tw2 = d_in[9];
  const void* tb2 = d_in[10];
  const void* mw1 = d_in[11];
  const void* mb1 = d_in[12];
  const void* mw2 = d_in[13];
  const void* mb2 = d_in[14];
  const void* mw3 = d_in[15];
  const void* mb3 = d_in[16];

  char* w8 = (char*)d_ws;
  float* mel_f32 = (float*)(w8 + 0);
  float* melh1 = (float*)(w8 + 20971520ull);
  float* mh2 = (float*)(w8 + 62914560ull);
  float* text_f32 = (float*)(w8 + 83886080ull);
  float* texth1 = (float*)(w8 + 100663296ull);
  float* val = (float*)(w8 + 0);

  float* te = (float*)(w8 + P + PO_TE);
  float* me = (float*)(w8 + P + PO_ME);
  float* na = (float*)(w8 + P + PO_NA);
  float* nb = (float*)(w8 + P + PO_NB);
  float* marr = (float*)(w8 + P + PO_M);
  float* rzarr = (float*)(w8 + P + PO_RZ);
  float* wt1 = (float*)(w8 + P + PO_W1);
  float* wt2 = (float*)(w8 + P + PO_W2);
  float* wt3 = (float*)(w8 + P + PO_W3);
  float* wt4 = (float*)(w8 + P + PO_W4);
  float* wt5 = (float*)(w8 + P + PO_W5);
  float* biasb = (float*)(w8 + P + PO_BIAS);
  uint32_t* dir = (uint32_t*)(w8 + P + PO_DIR);
  int* idxio = (int*)(w8 + P + PO_IDX);
  int* flag = (int*)(w8 + P + PO_FLAG);

  // outputs are float32
  float* soft = (float*)d_out;
  float* hard = soft + (size_t)NB_ * NS_ * NT_;
  float* rev = soft + 2 * (size_t)NB_ * NS_ * NT_;

  // dtype detect + converts
  k_detect<<<1, 256, 0, stream>>>((const uint32_t*)text, flag);
  k_cvt<<<(NB_ * NS_ * 256 + 255) / 256, 256, 0, stream>>>(text, text_f32, NB_ * NS_ * 256, flag);
  k_cvt<<<(NB_ * NT_ * 80 + 255) / 256, 256, 0, stream>>>(mel, mel_f32, NB_ * NT_ * 80, flag);
  k_cvt<<<2, 256, 0, stream>>>(tb1, biasb + BO_T1, 512, flag);
  k_cvt<<<1, 256, 0, stream>>>(tb2, biasb + BO_T2, 80, flag);
  k_cvt<<<1, 256, 0, stream>>>(mb1, biasb + BO_M1, 160, flag);
  k_cvt<<<1, 256, 0, stream>>>(mb2, biasb + BO_M2, 80, flag);
  k_cvt<<<1, 256, 0, stream>>>(mb3, biasb + BO_M3, 80, flag);

  // weight transposes
  k_wtrans<<<(512 * 256 * 3 + 255) / 256, 256, 0, stream>>>(tw1, wt1, 512, 256, 3, 512 * 256 * 3, flag);
  k_wtrans<<<(80 * 512 + 255) / 256, 256, 0, stream>>>(tw2, wt2, 80, 512, 1, 80 * 512, flag);
  k_wtrans<<<(160 * 80 * 3 + 255) / 256, 256, 0, stream>>>(mw1, wt3, 160, 80, 3, 160 * 80 * 3, flag);
  k_wtrans<<<(80 * 160 * 3 + 255) / 256, 256, 0, stream>>>(mw2, wt4, 80, 160, 3, 80 * 160 * 3, flag);
  k_wtrans<<<(80 * 80 + 255) / 256, 256, 0, stream>>>(mw3, wt5, 80, 80, 1, 80 * 80, flag);

  // encoders (pure f32)
  k_conv<80, 3, 160, 80, 5, 16, 11, 2, false><<<512 * 2, 256, 0, stream>>>(mel_f32, wt3, biasb + BO_M1, melh1, nullptr);
  k_conv<160, 3, 80, 80, 5, 32, 11, 2, false><<<512 * 1, 256, 0, stream>>>(melh1, wt4, biasb + BO_M2, mh2, nullptr);
  k_conv<80, 1, 80, 80, 5, 16, 11, 0, true><<<512 * 1, 256, 0, stream>>>(mh2, wt5, biasb + BO_M3, me, mel_len);
  k_conv<256, 3, 512, 128, 8, 32, 9, 1, false><<<128 * 4, 256, 0, stream>>>(text_f32, wt1, biasb + BO_T1, texth1, nullptr);
  k_conv<512, 1, 80, 80, 5, 32, 9, 0, true><<<128 * 1, 256, 0, stream>>>(texth1, wt2, biasb + BO_T2, te, src_len);

  // norms
  k_norms<<<(NB_ * NS_ * 4) / 256, 256, 0, stream>>>(te, na, NB_ * NS_);
  k_norms<<<(NB_ * NT_ * 4) / 256, 256, 0, stream>>>(me, nb, NB_ * NT_);

  // hard_A zero EARLY so its 128MB write traffic doesn't evict val from L3
  hipMemsetAsync(hard, 0, (size_t)NB_ * NS_ * NT_ * 4, stream);

  // softmax stats + finalize
  k_stats2<<<NB_ * 32, 256, 0, stream>>>(te, me, na, nb, src_len, mel_len, marr, rzarr);
  k_final3<<<NB_ * 8 * 32, 256, 0, stream>>>(te, me, na, nb, marr, rzarr, src_len, mel_len,
                                             val, soft, rev);

  // DP + backtrack
  k_dp<<<NB_, 192, 0, stream>>>(val, src_len, mel_len, dir);
  k_backtrack<<<NB_, 256, 0, stream>>>(dir, src_len, mel_len, hard, idxio, 0);
  k_backtrack<<<NB_, 256, 0, stream>>>(dir, src_len, mel_len, hard, idxio, 1);
}

// Round 15
// 1294.363 us; speedup vs baseline: 1.2903x; 1.0276x over previous
//
#include <hip/hip_runtime.h>
#include <hip/hip_bf16.h>
#include <cstdint>

// Problem constants
constexpr int NB_ = 32;     // batch
constexpr int NS_ = 512;    // text length S
constexpr int NT_ = 2048;   // mel length T
constexpr int DMEL = 80;    // embedding dim

// ---------------- workspace layout ----------------
constexpr size_t P = 134217728ull;  // persistent block base
constexpr size_t PO_TE   = 0ull;
constexpr size_t PO_ME   = 5242880ull;
constexpr size_t PO_NA   = 26214400ull;
constexpr size_t PO_NB   = 26279936ull;
constexpr size_t PO_M    = 26542080ull;
constexpr size_t PO_RZ   = 26804224ull;
constexpr size_t PO_W1   = 27066368ull;
constexpr size_t PO_W2   = 28639232ull;
constexpr size_t PO_W3   = 28803072ull;
constexpr size_t PO_W4   = 28956672ull;
constexpr size_t PO_W5   = 29110272ull;
constexpr size_t PO_BIAS = 29135872ull;
constexpr size_t PO_DIR  = 29139968ull;
constexpr size_t PO_IDX  = 33334272ull;
constexpr size_t PO_FLAG = 33334400ull;
constexpr size_t FULL_NEED = P + 33334528ull;

constexpr int BO_T1 = 0, BO_T2 = 512, BO_M1 = 592, BO_M2 = 752, BO_M3 = 832;

// ---------------- dtype detect: bf16 vs f32 probe on text ----------------
__global__ void k_detect(const uint32_t* __restrict__ w, int* __restrict__ flag) {
  __shared__ int red[256];
  const int tid = threadIdx.x;
  int cnt = 0;
  for (int i = tid; i < 4096; i += 256) {
    uint32_t e = (w[i] >> 7) & 0xFFu;
    cnt += (e >= 119u && e <= 129u) ? 1 : 0;
  }
  red[tid] = cnt;
  __syncthreads();
  for (int s = 128; s > 0; s >>= 1) {
    if (tid < s) red[tid] += red[tid + s];
    __syncthreads();
  }
  if (tid == 0) *flag = (red[0] > 2048) ? 1 : 0;
}

// ---------------- flag-branched convert to f32 ----------------
__global__ void k_cvt(const void* __restrict__ in, float* __restrict__ out, int n,
                      const int* __restrict__ flag) {
  const int i = blockIdx.x * 256 + threadIdx.x;
  if (i >= n) return;
  if (*flag) {
    uint16_t u = ((const uint16_t*)in)[i];
    out[i] = __uint_as_float((uint32_t)u << 16);
  } else {
    out[i] = ((const float*)in)[i];
  }
}

// ---------------- weight transpose ----------------
__global__ void k_wtrans(const void* __restrict__ w, float* __restrict__ wT,
                         int CO, int CI, int KW, int total, const int* __restrict__ flag) {
  int id = blockIdx.x * 256 + threadIdx.x;
  if (id >= total) return;
  int co = id % CO;
  int rest = id / CO;
  int ci = rest % CI;
  int tap = rest / CI;
  int src = (co * CI + ci) * KW + tap;
  if (*flag) {
    uint16_t u = ((const uint16_t*)w)[src];
    wT[id] = __uint_as_float((uint32_t)u << 16);
  } else {
    wT[id] = ((const float*)w)[src];
  }
}

// ---------------- conv1d K=1 as implicit GEMM (pure f32) ----------------
template <int CIN, int KW, int COUT, int NTILE, int NR, int KC, int LOG2L, int ACT, bool MASK>
__global__ __launch_bounds__(256) void k_conv(const float* __restrict__ x,
                                              const float* __restrict__ wT,
                                              const float* __restrict__ bias,
                                              float* __restrict__ y,
                                              const int* __restrict__ lenArr) {
  constexpr int L = 1 << LOG2L;
  constexpr int PAD = (KW - 1) / 2;
  constexpr int MT = 128;
  constexpr int APAD = 132;
  constexpr int BPAD = NTILE + 4;
  __shared__ float As[KC][APAD];
  __shared__ float Bs[KC][BPAD];

  const int tid = threadIdx.x;
  const int tx = tid & 15;
  const int ty = tid >> 4;
  constexpr int NBLK = COUT / NTILE;
  const int m0 = (blockIdx.x / NBLK) * MT;
  const int n0 = (blockIdx.x % NBLK) * NTILE;

  float acc[8][NR];
#pragma unroll
  for (int i = 0; i < 8; ++i)
#pragma unroll
    for (int j = 0; j < NR; ++j) acc[i][j] = 0.f;

  for (int tap = 0; tap < KW; ++tap) {
    for (int k0 = 0; k0 < CIN; k0 += KC) {
      __syncthreads();
      constexpr int AF4 = MT * KC / 4;
      constexpr int F4R = KC / 4;
      for (int f = tid; f < AF4; f += 256) {
        int row = f / F4R;
        int ko = (f % F4R) * 4;
        int r = m0 + row;
        int b = r >> LOG2L;
        int pos = (r & (L - 1)) + tap - PAD;
        float4 v = make_float4(0.f, 0.f, 0.f, 0.f);
        if (pos >= 0 && pos < L)
          v = *reinterpret_cast<const float4*>(
              &x[((size_t)(b << LOG2L) + pos) * CIN + k0 + ko]);
        As[ko + 0][row] = v.x;
        As[ko + 1][row] = v.y;
        As[ko + 2][row] = v.z;
        As[ko + 3][row] = v.w;
      }
      constexpr int BF4 = KC * NTILE / 4;
      constexpr int BF4R = NTILE / 4;
      for (int f = tid; f < BF4; f += 256) {
        int kk = f / BF4R;
        int no = (f % BF4R) * 4;
        float4 v = *reinterpret_cast<const float4*>(
            &wT[((size_t)(tap * CIN + k0 + kk)) * COUT + n0 + no]);
        *reinterpret_cast<float4*>(&Bs[kk][no]) = v;
      }
      __syncthreads();
#pragma unroll 8
      for (int kk = 0; kk < KC; ++kk) {
        float4 a0 = *reinterpret_cast<const float4*>(&As[kk][ty * 8]);
        float4 a1 = *reinterpret_cast<const float4*>(&As[kk][ty * 8 + 4]);
        float av[8] = {a0.x, a0.y, a0.z, a0.w, a1.x, a1.y, a1.z, a1.w};
        float bv[NR];
#pragma unroll
        for (int j = 0; j < NR; ++j) bv[j] = Bs[kk][tx * NR + j];
#pragma unroll
        for (int i = 0; i < 8; ++i)
#pragma unroll
          for (int j = 0; j < NR; ++j) acc[i][j] = fmaf(av[i], bv[j], acc[i][j]);
      }
    }
  }
#pragma unroll
  for (int i = 0; i < 8; ++i) {
    int r = m0 + ty * 8 + i;
    int b = r >> LOG2L;
    int pos = r & (L - 1);
    bool zero = MASK && (pos >= lenArr[b]);
#pragma unroll
    for (int j = 0; j < NR; ++j) {
      int c = n0 + tx * NR + j;
      float v = acc[i][j] + bias[c];
      if (ACT == 1) v = fmaxf(v, 0.f);
      if (ACT == 2) v = (v >= 0.f) ? v : 0.01f * v;
      if (zero) v = 0.f;
      y[(size_t)r * COUT + c] = v;
    }
  }
}

// ---------------- conv1d K=3: halo-staged A (once per k0), all taps inner ----
// As[kk][h], h in [0,130): global row g = m0+h-1. Output row r uses
// x[r+tap-1] -> h = (r-m0)+tap; sliding register window keeps reads aligned.
// Boundary: window [m0-1, m0+128] crosses a batch edge only at h=0 (iff
// m0%L==0) or h=129 (iff (m0+128)%L==0) -> zero those rows at stage time.
template <int CIN, int COUT, int NTILE, int NR, int KC, int LOG2L, int ACT>
__global__ __launch_bounds__(256) void k_conv3(const float* __restrict__ x,
                                               const float* __restrict__ wT,
                                               const float* __restrict__ bias,
                                               float* __restrict__ y) {
  constexpr int L = 1 << LOG2L;
  constexpr int MT = 128;
  constexpr int MT2 = MT + 2;       // 130 halo rows
  constexpr int APAD = 132;
  constexpr int BPAD = NTILE + 4;
  __shared__ float As[KC][APAD];
  __shared__ float Bs[3][KC][BPAD];

  const int tid = threadIdx.x;
  const int tx = tid & 15;
  const int ty = tid >> 4;
  constexpr int NBLK = COUT / NTILE;
  const int m0 = (blockIdx.x / NBLK) * MT;
  const int n0 = (blockIdx.x % NBLK) * NTILE;
  const bool zlo = (m0 & (L - 1)) == 0;
  const bool zhi = ((m0 + MT) & (L - 1)) == 0;
  constexpr int TOTR = NB_ << LOG2L;

  float acc[8][NR];
#pragma unroll
  for (int i = 0; i < 8; ++i)
#pragma unroll
    for (int j = 0; j < NR; ++j) acc[i][j] = 0.f;

  for (int k0 = 0; k0 < CIN; k0 += KC) {
    __syncthreads();
    // stage A with halo (once for all 3 taps)
    constexpr int F4R = KC / 4;
    for (int f = tid; f < MT2 * F4R; f += 256) {
      int h = f / F4R;
      int ko = (f % F4R) * 4;
      int g = m0 + h - 1;
      bool zero = (h == 0 && zlo) || (h == MT + 1 && zhi);
      int gc = g < 0 ? 0 : (g >= TOTR ? TOTR - 1 : g);
      float4 v = *reinterpret_cast<const float4*>(&x[(size_t)gc * CIN + k0 + ko]);
      if (zero) v = make_float4(0.f, 0.f, 0.f, 0.f);
      As[ko + 0][h] = v.x;
      As[ko + 1][h] = v.y;
      As[ko + 2][h] = v.z;
      As[ko + 3][h] = v.w;
    }
    // stage B for all 3 taps
    constexpr int BF4R = NTILE / 4;
    for (int f = tid; f < 3 * KC * BF4R; f += 256) {
      int tap = f / (KC * BF4R);
      int rem = f % (KC * BF4R);
      int kk = rem / BF4R;
      int no = (rem % BF4R) * 4;
      float4 v = *reinterpret_cast<const float4*>(
          &wT[((size_t)(tap * CIN + k0 + kk)) * COUT + n0 + no]);
      *reinterpret_cast<float4*>(&Bs[tap][kk][no]) = v;
    }
    __syncthreads();
#pragma unroll 4
    for (int kk = 0; kk < KC; ++kk) {
      float aw[10];
      float4 a0 = *reinterpret_cast<const float4*>(&As[kk][ty * 8]);
      float4 a1 = *reinterpret_cast<const float4*>(&As[kk][ty * 8 + 4]);
      float2 a2 = *reinterpret_cast<const float2*>(&As[kk][ty * 8 + 8]);
      aw[0] = a0.x; aw[1] = a0.y; aw[2] = a0.z; aw[3] = a0.w;
      aw[4] = a1.x; aw[5] = a1.y; aw[6] = a1.z; aw[7] = a1.w;
      aw[8] = a2.x; aw[9] = a2.y;
#pragma unroll
      for (int tap = 0; tap < 3; ++tap) {
        float bv[NR];
#pragma unroll
        for (int j = 0; j < NR; ++j) bv[j] = Bs[tap][kk][tx * NR + j];
#pragma unroll
        for (int i = 0; i < 8; ++i)
#pragma unroll
          for (int j = 0; j < NR; ++j)
            acc[i][j] = fmaf(aw[i + tap], bv[j], acc[i][j]);
      }
    }
  }
#pragma unroll
  for (int i = 0; i < 8; ++i) {
    int r = m0 + ty * 8 + i;
#pragma unroll
    for (int j = 0; j < NR; ++j) {
      int c = n0 + tx * NR + j;
      float v = acc[i][j] + bias[c];
      if (ACT == 1) v = fmaxf(v, 0.f);
      if (ACT == 2) v = (v >= 0.f) ? v : 0.01f * v;
      y[(size_t)r * COUT + c] = v;
    }
  }
}

// ---------------- row squared-norms ----------------
__global__ void k_norms(const float* __restrict__ e, float* __restrict__ out, int rows) {
  int tid = blockIdx.x * 256 + threadIdx.x;
  int row = tid >> 2, sub = tid & 3;
  if (row >= rows) return;
  const float* p = e + (size_t)row * DMEL;
  float s = 0.f;
#pragma unroll
  for (int j = 0; j < 5; ++j) {
    float4 v = *reinterpret_cast<const float4*>(&p[(sub + 4 * j) * 4]);
    s = fmaf(v.x, v.x, fmaf(v.y, v.y, fmaf(v.z, v.z, fmaf(v.w, v.w, s))));
  }
  s += __shfl_xor(s, 1);
  s += __shfl_xor(s, 2);
  if (sub == 0) out[row] = s;
}

// ---------------- softmax stats by recomputation ----------------
__global__ __launch_bounds__(256) void k_stats2(
    const float* __restrict__ te, const float* __restrict__ me,
    const float* __restrict__ na, const float* __restrict__ nb,
    const int* __restrict__ src_len, const int* __restrict__ mel_len,
    float* __restrict__ marr, float* __restrict__ rzarr) {
  const int b = blockIdx.x >> 5;
  const int t0 = (blockIdx.x & 31) << 6;
  __shared__ float Bt[DMEL][68];
  __shared__ float At[DMEL][68];
  __shared__ float redm[16][64];
  __shared__ float redz[16][64];
  const int tid = threadIdx.x;
  for (int f = tid; f < 64 * 20; f += 256) {
    int row = f / 20, ko = (f % 20) << 2;
    float4 v = *reinterpret_cast<const float4*>(
        &me[((size_t)b * NT_ + t0 + row) * DMEL + ko]);
    Bt[ko][row] = v.x; Bt[ko + 1][row] = v.y; Bt[ko + 2][row] = v.z; Bt[ko + 3][row] = v.w;
  }
  const int tx = tid & 15, sy = tid >> 4;
  const int sl = src_len[b], ml = mel_len[b];
  const float NEGINF = -__builtin_inff();
  float nbv[4], mACC[4], zACC[4];
#pragma unroll
  for (int j = 0; j < 4; ++j) {
    nbv[j] = nb[b * NT_ + t0 + (tx << 2) + j];
    mACC[j] = NEGINF;
    zACC[j] = 0.f;
  }
  for (int c = 0; c < 8; ++c) {
    const int s0 = c << 6;
    __syncthreads();
    for (int f = tid; f < 64 * 20; f += 256) {
      int row = f / 20, ko = (f % 20) << 2;
      float4 v = *reinterpret_cast<const float4*>(
          &te[((size_t)b * NS_ + s0 + row) * DMEL + ko]);
      At[ko][row] = v.x; At[ko + 1][row] = v.y; At[ko + 2][row] = v.z; At[ko + 3][row] = v.w;
    }
    __syncthreads();
    float acc[4][4];
#pragma unroll
    for (int i = 0; i < 4; ++i)
#pragma unroll
      for (int j = 0; j < 4; ++j) acc[i][j] = 0.f;
#pragma unroll 8
    for (int kk = 0; kk < DMEL; ++kk) {
      float4 a = *reinterpret_cast<const float4*>(&At[kk][sy << 2]);
      float4 bb = *reinterpret_cast<const float4*>(&Bt[kk][tx << 2]);
      float av[4] = {a.x, a.y, a.z, a.w}, bv[4] = {bb.x, bb.y, bb.z, bb.w};
#pragma unroll
      for (int i = 0; i < 4; ++i)
#pragma unroll
        for (int j = 0; j < 4; ++j) acc[i][j] = fmaf(av[i], bv[j], acc[i][j]);
    }
    float nav[4];
#pragma unroll
    for (int i = 0; i < 4; ++i) nav[i] = na[b * NS_ + s0 + (sy << 2) + i];
#pragma unroll
    for (int j = 0; j < 4; ++j) {
      const bool tvalid = (t0 + (tx << 2) + j) < ml;
      float ov[4];
      float mNew = mACC[j];
#pragma unroll
      for (int i = 0; i < 4; ++i) {
        float d2 = (nav[i] + nbv[j]) - 2.0f * acc[i][j];
        float dist = sqrtf(fmaxf(d2, 1e-12f));
        bool valid = ((s0 + (sy << 2) + i) < sl) && tvalid;
        ov[i] = valid ? -dist : -1e9f;
        mNew = fmaxf(mNew, ov[i]);
      }
      float scale = expf(mACC[j] - mNew);
      float zadd = 0.f;
#pragma unroll
      for (int i = 0; i < 4; ++i) zadd += expf(ov[i] - mNew);
      zACC[j] = zACC[j] * scale + zadd;
      mACC[j] = mNew;
    }
  }
#pragma unroll
  for (int j = 0; j < 4; ++j) {
    redm[sy][(tx << 2) + j] = mACC[j];
    redz[sy][(tx << 2) + j] = zACC[j];
  }
  __syncthreads();
  if (tid < 64) {
    float M = NEGINF, Z = 0.f;
#pragma unroll
    for (int y = 0; y < 16; ++y) {
      float m = redm[y][tid], z = redz[y][tid];
      float Mn = fmaxf(M, m);
      Z = Z * expf(M - Mn) + z * expf(m - Mn);
      M = Mn;
    }
    marr[b * NT_ + t0 + tid] = M;
    rzarr[b * NT_ + t0 + tid] = 1.0f / Z;
  }
}

// ---------------- finalize: soft/rev f32 out + f32 val for DP ----------------
__global__ __launch_bounds__(256) void k_final3(
    const float* __restrict__ te, const float* __restrict__ me,
    const float* __restrict__ na, const float* __restrict__ nb,
    const float* __restrict__ marr, const float* __restrict__ rzarr,
    const int* __restrict__ src_len, const int* __restrict__ mel_len,
    float* __restrict__ val,
    float* __restrict__ soft, float* __restrict__ rev) {
  const int idx = blockIdx.x;
  const int tt = idx & 31;
  const int st = (idx >> 5) & 7;
  const int b = idx >> 8;
  const int s0 = st << 6, t0 = tt << 6;
  __shared__ float At[DMEL][68];
  __shared__ float Bt[DMEL][68];
  __shared__ float pl[64][65];
  const int tid = threadIdx.x;
  for (int f = tid; f < 64 * 20; f += 256) {
    int row = f / 20, ko = (f % 20) << 2;
    float4 v = *reinterpret_cast<const float4*>(
        &te[((size_t)b * NS_ + s0 + row) * DMEL + ko]);
    At[ko][row] = v.x; At[ko + 1][row] = v.y; At[ko + 2][row] = v.z; At[ko + 3][row] = v.w;
  }
  for (int f = tid; f < 64 * 20; f += 256) {
    int row = f / 20, ko = (f % 20) << 2;
    float4 v = *reinterpret_cast<const float4*>(
        &me[((size_t)b * NT_ + t0 + row) * DMEL + ko]);
    Bt[ko][row] = v.x; Bt[ko + 1][row] = v.y; Bt[ko + 2][row] = v.z; Bt[ko + 3][row] = v.w;
  }
  __syncthreads();
  const int sy = tid & 15, tx = tid >> 4;  // lane varies in s (coalesced val store)
  float acc[4][4];
#pragma unroll
  for (int i = 0; i < 4; ++i)
#pragma unroll
    for (int j = 0; j < 4; ++j) acc[i][j] = 0.f;
#pragma unroll 8
  for (int kk = 0; kk < DMEL; ++kk) {
    float4 a = *reinterpret_cast<const float4*>(&At[kk][sy << 2]);
    float4 bb = *reinterpret_cast<const float4*>(&Bt[kk][tx << 2]);
    float av[4] = {a.x, a.y, a.z, a.w}, bv[4] = {bb.x, bb.y, bb.z, bb.w};
#pragma unroll
    for (int i = 0; i < 4; ++i)
#pragma unroll
      for (int j = 0; j < 4; ++j) acc[i][j] = fmaf(av[i], bv[j], acc[i][j]);
  }
  const int sl = src_len[b], ml = mel_len[b];
  float nav[4], nbv[4];
#pragma unroll
  for (int i = 0; i < 4; ++i) nav[i] = na[b * NS_ + s0 + (sy << 2) + i];
#pragma unroll
  for (int j = 0; j < 4; ++j) nbv[j] = nb[b * NT_ + t0 + (tx << 2) + j];
#pragma unroll
  for (int j = 0; j < 4; ++j) {
    const int t = t0 + (tx << 2) + j;
    const bool tvalid = t < ml;
    const float mv = marr[b * NT_ + t];
    const float rzv = rzarr[b * NT_ + t];
    float pv[4];
#pragma unroll
    for (int i = 0; i < 4; ++i) {
      float d2 = (nav[i] + nbv[j]) - 2.0f * acc[i][j];
      float dist = sqrtf(fmaxf(d2, 1e-12f));
      bool valid = ((s0 + (sy << 2) + i) < sl) && tvalid;
      float ov = valid ? -dist : -1e9f;
      float p = tvalid ? expf(ov - mv) * rzv : 0.f;
      pv[i] = p;
      pl[(tx << 2) + j][(sy << 2) + i] = p;
    }
    float4 o = make_float4(pv[0], pv[1], pv[2], pv[3]);
    *reinterpret_cast<float4*>(&val[((size_t)b * NT_ + t) * NS_ + s0 + (sy << 2)]) = o;
  }
  __syncthreads();
  const int lane = tid & 63, w = tid >> 6;
#pragma unroll 4
  for (int i = 0; i < 16; ++i) {
    const int s_loc = (w << 4) + i;
    const int s = s0 + s_loc;
    float p = pl[lane][s_loc];
    size_t o = ((size_t)b * NS_ + s) * NT_ + t0 + lane;
    soft[o] = p;
    bool r = (s >= sl) || ((t0 + lane) >= ml);
    rev[o] = r ? 1.0f : 0.0f;
  }
}

// lane i <- lane i-1 via DPP wave_shr:1 (VALU, no LDS pipe). Lane 0 -> 0.
__device__ __forceinline__ float dp_shr1(float x) {
  int r = __builtin_amdgcn_update_dpp(0, __float_as_int(x), 0x138, 0xF, 0xF, true);
  return __int_as_float(r);
}

// RAW barrier: lgkmcnt(0) for cross-wave ds_write visibility, no vmcnt drain.
__device__ __forceinline__ void dp_bar() {
  asm volatile("s_waitcnt lgkmcnt(0)" ::: "memory");
  __builtin_amdgcn_sched_barrier(0);
  __builtin_amdgcn_s_barrier();
}

// Consumer chunk body: 16 rows, 4-row register batches. MASKED = apply (s<=t).
#define DP_CHUNK(MASKED)                                                      \
  _Pragma("unroll")                                                           \
  for (int rb8 = 0; rb8 < 4; ++rb8) {                                         \
    float4 d0[4], d1[4];                                                      \
    _Pragma("unroll")                                                         \
    for (int rr = 0; rr < 4; ++rr) {                                          \
      const float* rp = rowbase + (((rb8 << 2) + rr) << 9);                   \
      d0[rr] = *reinterpret_cast<const float4*>(rp + (lane << 2));            \
      d1[rr] = *reinterpret_cast<const float4*>(rp + 256 + (lane << 2));      \
    }                                                                         \
    _Pragma("unroll")                                                         \
    for (int rr = 0; rr < 4; ++rr) {                                          \
      const int t = tbase + (rb8 << 2) + rr;                                  \
      float cc[8] = {d0[rr].x, d0[rr].y, d0[rr].z, d0[rr].w,                  \
                     d1[rr].x, d1[rr].y, d1[rr].z, d1[rr].w};                 \
      const int sh = t & 31;                                                  \
      if (t < ml) {                                                           \
        float up = dp_shr1(v[7]);                                             \
        float prev = (lane == 0) ? NEGINF : up;                               \
        _Pragma("unroll")                                                     \
        for (int j = 0; j < 8; ++j) {                                         \
          float cur = v[j];                                                   \
          bool keep = cur >= prev;                                            \
          float vm = fmaxf(cur, prev);                                        \
          float vn;                                                           \
          if (MASKED) {                                                       \
            int s = (lane << 3) + j;                                          \
            vn = (s <= t) ? vm + cc[j] : NEGINF;                              \
          } else {                                                            \
            vn = vm + cc[j];                                                  \
          }                                                                   \
          uint32_t bit = keep ? 1u : inv[j];                                  \
          bw[j] |= bit << sh;                                                 \
          v[j] = vn;                                                          \
          prev = cur;                                                         \
        }                                                                     \
      } else {                                                                \
        _Pragma("unroll")                                                     \
        for (int j = 0; j < 8; ++j) bw[j] |= 1u << sh;                        \
      }                                                                       \
    }                                                                         \
  }

// ---------------- DP forward scan: 1 consumer + 2 reg-staging producer waves ----
__global__ __launch_bounds__(192) void k_dp(const float* __restrict__ val,
                                            const int* __restrict__ src_len,
                                            const int* __restrict__ mel_len,
                                            uint32_t* __restrict__ dir) {
  __shared__ float buf[2][16][512];  // 64 KB double buffer
  const int b = blockIdx.x;
  const int wv = threadIdx.x >> 6;   // 0 = consumer, 1..2 = producers
  const int lane = threadIdx.x & 63;
  const float* base = val + (size_t)b * NT_ * NS_;
  const int sl = src_len[b];
  const int ml = mel_len[b];
  const float NEGINF = -__builtin_inff();
  int ca = ((ml + 31) >> 5) << 1;
  const int C_act = ca > 128 ? 128 : ca;

  float4 ra[8], rb[8];
  const int r0 = (wv - 1) << 3;

  float v[8];
  uint32_t bw[8], inv[8];
#pragma unroll
  for (int j = 0; j < 8; ++j) {
    v[j] = 0.0f;
    bw[j] = 0u;
    int s = (lane << 3) + j;
    inv[j] = (s < sl) ? 0u : 1u;
  }

  if (wv > 0) {
#pragma unroll
    for (int rr = 0; rr < 8; ++rr) {
      const float* g = base + (size_t)(r0 + rr) * NS_;
      ra[rr] = *reinterpret_cast<const float4*>(g + (lane << 3));
      rb[rr] = *reinterpret_cast<const float4*>(g + (lane << 3) + 4);
    }
#pragma unroll
    for (int rr = 0; rr < 8; ++rr) {
      float* l = &buf[0][r0 + rr][0];
      *reinterpret_cast<float4*>(l + (lane << 2)) = ra[rr];
      *reinterpret_cast<float4*>(l + 256 + (lane << 2)) = rb[rr];
    }
#pragma unroll
    for (int rr = 0; rr < 8; ++rr) {
      const float* g = base + (size_t)(16 + r0 + rr) * NS_;
      ra[rr] = *reinterpret_cast<const float4*>(g + (lane << 3));
      rb[rr] = *reinterpret_cast<const float4*>(g + (lane << 3) + 4);
    }
  }
  dp_bar();

  for (int c = 0; c < C_act; ++c) {
    if (wv > 0) {
      if (c + 1 < C_act) {
        const int nb = (c + 1) & 1;
#pragma unroll
        for (int rr = 0; rr < 8; ++rr) {
          float* l = &buf[nb][r0 + rr][0];
          *reinterpret_cast<float4*>(l + (lane << 2)) = ra[rr];
          *reinterpret_cast<float4*>(l + 256 + (lane << 2)) = rb[rr];
        }
      }
      if (c + 2 < C_act) {
        const float* cb = base + ((size_t)(c + 2) * 16 + r0) * NS_;
#pragma unroll
        for (int rr = 0; rr < 8; ++rr) {
          const float* g = cb + (size_t)rr * NS_;
          ra[rr] = *reinterpret_cast<const float4*>(g + (lane << 3));
          rb[rr] = *reinterpret_cast<const float4*>(g + (lane << 3) + 4);
        }
      }
    } else {
      const float* rowbase = &buf[c & 1][0][0];
      const int tbase = c << 4;
      if (c < 32) {
        DP_CHUNK(true)
      } else {
        DP_CHUNK(false)
      }
      if (c & 1) {
        const int c32 = c >> 1;
#pragma unroll
        for (int j = 0; j < 8; ++j) {
          dir[((size_t)(b * NS_) + (lane << 3) + j) * 64 + c32] = bw[j];
          bw[j] = 0u;
        }
      }
    }
    dp_bar();
  }
  if (wv == 0) {
    for (int c32 = C_act >> 1; c32 < 64; ++c32) {
#pragma unroll
      for (int j = 0; j < 8; ++j)
        dir[((size_t)(b * NS_) + (lane << 3) + j) * 64 + c32] = 0xFFFFFFFFu;
    }
  }
}

// ---------------- backtrack (two half-T phases) ----------------
__global__ __launch_bounds__(256) void k_backtrack(
    const uint32_t* __restrict__ dir, const int* __restrict__ src_len,
    const int* __restrict__ mel_len, float* __restrict__ hard,
    int* __restrict__ idxio, int phase) {
  __shared__ uint32_t dl[NS_ * 32];
  const int b = blockIdx.x, tid = threadIdx.x;
  const uint32_t* db = dir + (size_t)b * NS_ * 64;
  const int woff = phase ? 0 : 32;
  for (int f = tid; f < 4096; f += 256) {
    int s = f >> 3;
    int wo = (f & 7) << 2;
    *reinterpret_cast<uint4*>(&dl[s * 32 + wo]) =
        *reinterpret_cast<const uint4*>(&db[s * 64 + woff + wo]);
  }
  __syncthreads();
  if (tid == 0) {
    const int ml = mel_len[b];
    int idx = phase ? idxio[b] : (src_len[b] - 1);
    if (idx < 0) idx = 0;
    if (idx > NS_ - 1) idx = NS_ - 1;
    const int thi = phase ? 1023 : 2047;
    const int tlo = phase ? 0 : 1024;
    int cw = -1, ci = -1;
    uint32_t w = 0;
    for (int t = thi; t >= tlo; --t) {
      int wi = t >> 5;
      if (wi != cw || idx != ci) {
        w = dl[idx * 32 + (wi - woff)];
        cw = wi;
        ci = idx;
      }
      if (t < ml) hard[((size_t)(b * NS_) + idx) * NT_ + t] = 1.0f;
      int step = (int)((w >> (t & 31)) & 1) - 1;
      idx += step;
      if (idx < 0) idx = 0;
    }
    if (!phase) idxio[b] = idx;
  }
}

// ---------------- host launch ----------------
extern "C" void kernel_launch(void* const* d_in, const int* in_sizes, int n_in,
                              void* d_out, int out_size, void* d_ws, size_t ws_size,
                              hipStream_t stream) {
  if (n_in != 17) return;
  if (ws_size < FULL_NEED) return;

  const void* text = d_in[0];
  const void* mel = d_in[1];
  const int* src_len = (const int*)d_in[2];
  const int* mel_len = (const int*)d_in[3];
  const void* tw1 = d_in[7];
  const void* tb1 = d_in[8];
  const void* tw2 = d_in[9];
  const void* tb2 = d_in[10];
  const void* mw1 = d_in[11];
  const void* mb1 = d_in[12];
  const void* mw2 = d_in[13];
  const void* mb2 = d_in[14];
  const void* mw3 = d_in[15];
  const void* mb3 = d_in[16];

  char* w8 = (char*)d_ws;
  float* mel_f32 = (float*)(w8 + 0);
  float* melh1 = (float*)(w8 + 20971520ull);
  float* mh2 = (float*)(w8 + 62914560ull);
  float* text_f32 = (float*)(w8 + 83886080ull);
  float* texth1 = (float*)(w8 + 100663296ull);
  float* val = (float*)(w8 + 0);

  float* te = (float*)(w8 + P + PO_TE);
  float* me = (float*)(w8 + P + PO_ME);
  float* na = (float*)(w8 + P + PO_NA);
  float* nb = (float*)(w8 + P + PO_NB);
  float* marr = (float*)(w8 + P + PO_M);
  float* rzarr = (float*)(w8 + P + PO_RZ);
  float* wt1 = (float*)(w8 + P + PO_W1);
  float* wt2 = (float*)(w8 + P + PO_W2);
  float* wt3 = (float*)(w8 + P + PO_W3);
  float* wt4 = (float*)(w8 + P + PO_W4);
  float* wt5 = (float*)(w8 + P + PO_W5);
  float* biasb = (float*)(w8 + P + PO_BIAS);
  uint32_t* dir = (uint32_t*)(w8 + P + PO_DIR);
  int* idxio = (int*)(w8 + P + PO_IDX);
  int* flag = (int*)(w8 + P + PO_FLAG);

  // outputs are float32
  float* soft = (float*)d_out;
  float* hard = soft + (size_t)NB_ * NS_ * NT_;
  float* rev = soft + 2 * (size_t)NB_ * NS_ * NT_;

  // dtype detect + converts
  k_detect<<<1, 256, 0, stream>>>((const uint32_t*)text, flag);
  k_cvt<<<(NB_ * NS_ * 256 + 255) / 256, 256, 0, stream>>>(text, text_f32, NB_ * NS_ * 256, flag);
  k_cvt<<<(NB_ * NT_ * 80 + 255) / 256, 256, 0, stream>>>(mel, mel_f32, NB_ * NT_ * 80, flag);
  k_cvt<<<2, 256, 0, stream>>>(tb1, biasb + BO_T1, 512, flag);
  k_cvt<<<1, 256, 0, stream>>>(tb2, biasb + BO_T2, 80, flag);
  k_cvt<<<1, 256, 0, stream>>>(mb1, biasb + BO_M1, 160, flag);
  k_cvt<<<1, 256, 0, stream>>>(mb2, biasb + BO_M2, 80, flag);
  k_cvt<<<1, 256, 0, stream>>>(mb3, biasb + BO_M3, 80, flag);

  // weight transposes
  k_wtrans<<<(512 * 256 * 3 + 255) / 256, 256, 0, stream>>>(tw1, wt1, 512, 256, 3, 512 * 256 * 3, flag);
  k_wtrans<<<(80 * 512 + 255) / 256, 256, 0, stream>>>(tw2, wt2, 80, 512, 1, 80 * 512, flag);
  k_wtrans<<<(160 * 80 * 3 + 255) / 256, 256, 0, stream>>>(mw1, wt3, 160, 80, 3, 160 * 80 * 3, flag);
  k_wtrans<<<(80 * 160 * 3 + 255) / 256, 256, 0, stream>>>(mw2, wt4, 80, 160, 3, 80 * 160 * 3, flag);
  k_wtrans<<<(80 * 80 + 255) / 256, 256, 0, stream>>>(mw3, wt5, 80, 80, 1, 80 * 80, flag);

  // encoders: KW=3 convs use halo-staged k_conv3 (A staged once per k0)
  k_conv3<80, 160, 80, 5, 16, 11, 2><<<512 * 2, 256, 0, stream>>>(mel_f32, wt3, biasb + BO_M1, melh1);
  k_conv3<160, 80, 80, 5, 32, 11, 2><<<512 * 1, 256, 0, stream>>>(melh1, wt4, biasb + BO_M2, mh2);
  k_conv<80, 1, 80, 80, 5, 16, 11, 0, true><<<512 * 1, 256, 0, stream>>>(mh2, wt5, biasb + BO_M3, me, mel_len);
  k_conv3<256, 512, 128, 8, 32, 9, 1><<<128 * 4, 256, 0, stream>>>(text_f32, wt1, biasb + BO_T1, texth1);
  k_conv<512, 1, 80, 80, 5, 32, 9, 0, true><<<128 * 1, 256, 0, stream>>>(texth1, wt2, biasb + BO_T2, te, src_len);

  // norms
  k_norms<<<(NB_ * NS_ * 4) / 256, 256, 0, stream>>>(te, na, NB_ * NS_);
  k_norms<<<(NB_ * NT_ * 4) / 256, 256, 0, stream>>>(me, nb, NB_ * NT_);

  // hard_A zero EARLY so its 128MB write traffic doesn't evict val from L3
  hipMemsetAsync(hard, 0, (size_t)NB_ * NS_ * NT_ * 4, stream);

  // softmax stats + finalize
  k_stats2<<<NB_ * 32, 256, 0, stream>>>(te, me, na, nb, src_len, mel_len, marr, rzarr);
  k_final3<<<NB_ * 8 * 32, 256, 0, stream>>>(te, me, na, nb, marr, rzarr, src_len, mel_len,
                                             val, soft, rev);

  // DP + backtrack
  k_dp<<<NB_, 192, 0, stream>>>(val, src_len, mel_len, dir);
  k_backtrack<<<NB_, 256, 0, stream>>>(dir, src_len, mel_len, hard, idxio, 0);
  k_backtrack<<<NB_, 256, 0, stream>>>(dir, src_len, mel_len, hard, idxio, 1);
}

// Round 16
// 1137.437 us; speedup vs baseline: 1.4683x; 1.1380x over previous
//
#include <hip/hip_runtime.h>
#include <hip/hip_bf16.h>
#include <cstdint>

// Problem constants
constexpr int NB_ = 32;     // batch
constexpr int NS_ = 512;    // text length S
constexpr int NT_ = 2048;   // mel length T
constexpr int DMEL = 80;    // embedding dim

// ---------------- workspace layout ----------------
// Scratch [0, P): melh1 [0, 41.9M), mh2 [41.9M, 62.9M), texth1 [62.9M, 96.5M)
// all consumed before val (B,T,S) f32 [0, 134.2M) is written by k_stats2.
constexpr size_t P = 134217728ull;  // persistent block base
constexpr size_t PO_TE   = 0ull;           // te (B,S,80) f32
constexpr size_t PO_ME   = 5242880ull;     // me (B,T,80) f32
constexpr size_t PO_NA   = 26214400ull;    // text norms (B,S)
constexpr size_t PO_NB   = 26279936ull;    // mel norms (B,T)
constexpr size_t PO_M    = 26542080ull;    // col max (B,T)
constexpr size_t PO_RZ   = 26804224ull;    // 1/Z (B,T)
constexpr size_t PO_W1   = 27066368ull;
constexpr size_t PO_W2   = 28639232ull;
constexpr size_t PO_W3   = 28803072ull;
constexpr size_t PO_W4   = 28956672ull;
constexpr size_t PO_W5   = 29110272ull;
constexpr size_t PO_DIR  = 29139968ull;    // direction bits (B,S,64 u32)
constexpr size_t FULL_NEED = P + 33334528ull;

// ---------------- weight transpose: w(CO,CI,KW) -> wT[(tap*CI+ci)*CO+co] ----
__global__ void k_wtrans(const float* __restrict__ w, float* __restrict__ wT,
                         int CO, int CI, int KW, int total) {
  int id = blockIdx.x * 256 + threadIdx.x;
  if (id >= total) return;
  int co = id % CO;
  int rest = id / CO;
  int ci = rest % CI;
  int tap = rest / CI;
  wT[id] = w[(co * CI + ci) * KW + tap];
}

// ---------------- conv1d K=1 as implicit GEMM, optional fused row-norm ------
template <int CIN, int COUT, int NTILE, int NR, int KC, int LOG2L, int ACT,
          bool MASK, bool NORM>
__global__ __launch_bounds__(256) void k_conv(const float* __restrict__ x,
                                              const float* __restrict__ wT,
                                              const float* __restrict__ bias,
                                              float* __restrict__ y,
                                              const int* __restrict__ lenArr,
                                              float* __restrict__ normout) {
  constexpr int L = 1 << LOG2L;
  constexpr int MT = 128;
  constexpr int APAD = 132;
  constexpr int BPAD = NTILE + 4;
  __shared__ float As[KC][APAD];
  __shared__ float Bs[KC][BPAD];

  const int tid = threadIdx.x;
  const int tx = tid & 15;
  const int ty = tid >> 4;
  constexpr int NBLK = COUT / NTILE;
  const int m0 = (blockIdx.x / NBLK) * MT;
  const int n0 = (blockIdx.x % NBLK) * NTILE;

  float acc[8][NR];
#pragma unroll
  for (int i = 0; i < 8; ++i)
#pragma unroll
    for (int j = 0; j < NR; ++j) acc[i][j] = 0.f;

  for (int k0 = 0; k0 < CIN; k0 += KC) {
    __syncthreads();
    constexpr int AF4 = MT * KC / 4;
    constexpr int F4R = KC / 4;
    for (int f = tid; f < AF4; f += 256) {
      int row = f / F4R;
      int ko = (f % F4R) * 4;
      int r = m0 + row;
      float4 v = *reinterpret_cast<const float4*>(&x[(size_t)r * CIN + k0 + ko]);
      As[ko + 0][row] = v.x;
      As[ko + 1][row] = v.y;
      As[ko + 2][row] = v.z;
      As[ko + 3][row] = v.w;
    }
    constexpr int BF4 = KC * NTILE / 4;
    constexpr int BF4R = NTILE / 4;
    for (int f = tid; f < BF4; f += 256) {
      int kk = f / BF4R;
      int no = (f % BF4R) * 4;
      float4 v = *reinterpret_cast<const float4*>(
          &wT[((size_t)(k0 + kk)) * COUT + n0 + no]);
      *reinterpret_cast<float4*>(&Bs[kk][no]) = v;
    }
    __syncthreads();
#pragma unroll 8
    for (int kk = 0; kk < KC; ++kk) {
      float4 a0 = *reinterpret_cast<const float4*>(&As[kk][ty * 8]);
      float4 a1 = *reinterpret_cast<const float4*>(&As[kk][ty * 8 + 4]);
      float av[8] = {a0.x, a0.y, a0.z, a0.w, a1.x, a1.y, a1.z, a1.w};
      float bv[NR];
#pragma unroll
      for (int j = 0; j < NR; ++j) bv[j] = Bs[kk][tx * NR + j];
#pragma unroll
      for (int i = 0; i < 8; ++i)
#pragma unroll
        for (int j = 0; j < NR; ++j) acc[i][j] = fmaf(av[i], bv[j], acc[i][j]);
    }
  }
#pragma unroll
  for (int i = 0; i < 8; ++i) {
    int r = m0 + ty * 8 + i;
    int b = r >> LOG2L;
    int pos = r & (L - 1);
    bool zero = MASK && (pos >= lenArr[b]);
    float sq = 0.f;
#pragma unroll
    for (int j = 0; j < NR; ++j) {
      int c = n0 + tx * NR + j;
      float v = acc[i][j] + bias[c];
      if (ACT == 1) v = fmaxf(v, 0.f);
      if (ACT == 2) v = (v >= 0.f) ? v : 0.01f * v;
      if (zero) v = 0.f;
      y[(size_t)r * COUT + c] = v;
      if (NORM) sq = fmaf(v, v, sq);
    }
    if (NORM) {
      sq += __shfl_xor(sq, 1);
      sq += __shfl_xor(sq, 2);
      sq += __shfl_xor(sq, 4);
      sq += __shfl_xor(sq, 8);
      if (tx == 0) normout[r] = sq;
    }
  }
}

// ---------------- conv1d K=3: halo-staged A (once per k0), all taps inner ----
template <int CIN, int COUT, int NTILE, int NR, int KC, int LOG2L, int ACT>
__global__ __launch_bounds__(256) void k_conv3(const float* __restrict__ x,
                                               const float* __restrict__ wT,
                                               const float* __restrict__ bias,
                                               float* __restrict__ y) {
  constexpr int L = 1 << LOG2L;
  constexpr int MT = 128;
  constexpr int MT2 = MT + 2;
  constexpr int APAD = 132;
  constexpr int BPAD = NTILE + 4;
  __shared__ float As[KC][APAD];
  __shared__ float Bs[3][KC][BPAD];

  const int tid = threadIdx.x;
  const int tx = tid & 15;
  const int ty = tid >> 4;
  constexpr int NBLK = COUT / NTILE;
  const int m0 = (blockIdx.x / NBLK) * MT;
  const int n0 = (blockIdx.x % NBLK) * NTILE;
  const bool zlo = (m0 & (L - 1)) == 0;
  const bool zhi = ((m0 + MT) & (L - 1)) == 0;
  constexpr int TOTR = NB_ << LOG2L;

  float acc[8][NR];
#pragma unroll
  for (int i = 0; i < 8; ++i)
#pragma unroll
    for (int j = 0; j < NR; ++j) acc[i][j] = 0.f;

  for (int k0 = 0; k0 < CIN; k0 += KC) {
    __syncthreads();
    constexpr int F4R = KC / 4;
    for (int f = tid; f < MT2 * F4R; f += 256) {
      int h = f / F4R;
      int ko = (f % F4R) * 4;
      int g = m0 + h - 1;
      bool zero = (h == 0 && zlo) || (h == MT + 1 && zhi);
      int gc = g < 0 ? 0 : (g >= TOTR ? TOTR - 1 : g);
      float4 v = *reinterpret_cast<const float4*>(&x[(size_t)gc * CIN + k0 + ko]);
      if (zero) v = make_float4(0.f, 0.f, 0.f, 0.f);
      As[ko + 0][h] = v.x;
      As[ko + 1][h] = v.y;
      As[ko + 2][h] = v.z;
      As[ko + 3][h] = v.w;
    }
    constexpr int BF4R = NTILE / 4;
    for (int f = tid; f < 3 * KC * BF4R; f += 256) {
      int tap = f / (KC * BF4R);
      int rem = f % (KC * BF4R);
      int kk = rem / BF4R;
      int no = (rem % BF4R) * 4;
      float4 v = *reinterpret_cast<const float4*>(
          &wT[((size_t)(tap * CIN + k0 + kk)) * COUT + n0 + no]);
      *reinterpret_cast<float4*>(&Bs[tap][kk][no]) = v;
    }
    __syncthreads();
#pragma unroll 4
    for (int kk = 0; kk < KC; ++kk) {
      float aw[10];
      float4 a0 = *reinterpret_cast<const float4*>(&As[kk][ty * 8]);
      float4 a1 = *reinterpret_cast<const float4*>(&As[kk][ty * 8 + 4]);
      float2 a2 = *reinterpret_cast<const float2*>(&As[kk][ty * 8 + 8]);
      aw[0] = a0.x; aw[1] = a0.y; aw[2] = a0.z; aw[3] = a0.w;
      aw[4] = a1.x; aw[5] = a1.y; aw[6] = a1.z; aw[7] = a1.w;
      aw[8] = a2.x; aw[9] = a2.y;
#pragma unroll
      for (int tap = 0; tap < 3; ++tap) {
        float bv[NR];
#pragma unroll
        for (int j = 0; j < NR; ++j) bv[j] = Bs[tap][kk][tx * NR + j];
#pragma unroll
        for (int i = 0; i < 8; ++i)
#pragma unroll
          for (int j = 0; j < NR; ++j)
            acc[i][j] = fmaf(aw[i + tap], bv[j], acc[i][j]);
      }
    }
  }
#pragma unroll
  for (int i = 0; i < 8; ++i) {
    int r = m0 + ty * 8 + i;
#pragma unroll
    for (int j = 0; j < NR; ++j) {
      int c = n0 + tx * NR + j;
      float v = acc[i][j] + bias[c];
      if (ACT == 1) v = fmaxf(v, 0.f);
      if (ACT == 2) v = (v >= 0.f) ? v : 0.01f * v;
      y[(size_t)r * COUT + c] = v;
    }
  }
}

// ---------------- stats + logits: writes val = masked(-dist) + marr/rzarr ----
// Role map: sy = tid&15 (s-quads, lane-contiguous), tx = tid>>4 (t-quads)
// -> val float4 stores are coalesced over lanes.
__global__ __launch_bounds__(256) void k_stats2(
    const float* __restrict__ te, const float* __restrict__ me,
    const float* __restrict__ na, const float* __restrict__ nb,
    const int* __restrict__ src_len, const int* __restrict__ mel_len,
    float* __restrict__ marr, float* __restrict__ rzarr,
    float* __restrict__ val) {
  const int b = blockIdx.x >> 5;
  const int t0 = (blockIdx.x & 31) << 6;
  __shared__ float Bt[DMEL][68];
  __shared__ float At[DMEL][68];
  __shared__ float redm[16][64];
  __shared__ float redz[16][64];
  const int tid = threadIdx.x;
  for (int f = tid; f < 64 * 20; f += 256) {
    int row = f / 20, ko = (f % 20) << 2;
    float4 v = *reinterpret_cast<const float4*>(
        &me[((size_t)b * NT_ + t0 + row) * DMEL + ko]);
    Bt[ko][row] = v.x; Bt[ko + 1][row] = v.y; Bt[ko + 2][row] = v.z; Bt[ko + 3][row] = v.w;
  }
  const int sy = tid & 15, tx = tid >> 4;
  const int sl = src_len[b], ml = mel_len[b];
  const float NEGINF = -__builtin_inff();
  float nbv[4], mACC[4], zACC[4];
#pragma unroll
  for (int j = 0; j < 4; ++j) {
    nbv[j] = nb[b * NT_ + t0 + (tx << 2) + j];
    mACC[j] = NEGINF;
    zACC[j] = 0.f;
  }
  for (int c = 0; c < 8; ++c) {
    const int s0 = c << 6;
    __syncthreads();
    for (int f = tid; f < 64 * 20; f += 256) {
      int row = f / 20, ko = (f % 20) << 2;
      float4 v = *reinterpret_cast<const float4*>(
          &te[((size_t)b * NS_ + s0 + row) * DMEL + ko]);
      At[ko][row] = v.x; At[ko + 1][row] = v.y; At[ko + 2][row] = v.z; At[ko + 3][row] = v.w;
    }
    __syncthreads();
    float acc[4][4];
#pragma unroll
    for (int i = 0; i < 4; ++i)
#pragma unroll
      for (int j = 0; j < 4; ++j) acc[i][j] = 0.f;
#pragma unroll 8
    for (int kk = 0; kk < DMEL; ++kk) {
      float4 a = *reinterpret_cast<const float4*>(&At[kk][sy << 2]);
      float4 bb = *reinterpret_cast<const float4*>(&Bt[kk][tx << 2]);
      float av[4] = {a.x, a.y, a.z, a.w}, bv[4] = {bb.x, bb.y, bb.z, bb.w};
#pragma unroll
      for (int i = 0; i < 4; ++i)
#pragma unroll
        for (int j = 0; j < 4; ++j) acc[i][j] = fmaf(av[i], bv[j], acc[i][j]);
    }
    float nav[4];
#pragma unroll
    for (int i = 0; i < 4; ++i) nav[i] = na[b * NS_ + s0 + (sy << 2) + i];
#pragma unroll
    for (int j = 0; j < 4; ++j) {
      const int t = t0 + (tx << 2) + j;
      const bool tvalid = t < ml;
      float ov[4];
      float mNew = mACC[j];
#pragma unroll
      for (int i = 0; i < 4; ++i) {
        float d2 = (nav[i] + nbv[j]) - 2.0f * acc[i][j];
        float dist = sqrtf(fmaxf(d2, 1e-12f));
        bool valid = ((s0 + (sy << 2) + i) < sl) && tvalid;
        ov[i] = valid ? -dist : -1e9f;
        mNew = fmaxf(mNew, ov[i]);
      }
      float scale = expf(mACC[j] - mNew);
      float zadd = 0.f;
#pragma unroll
      for (int i = 0; i < 4; ++i) zadd += expf(ov[i] - mNew);
      zACC[j] = zACC[j] * scale + zadd;
      mACC[j] = mNew;
      float4 o = make_float4(ov[0], ov[1], ov[2], ov[3]);
      *reinterpret_cast<float4*>(&val[((size_t)b * NT_ + t) * NS_ + s0 + (sy << 2)]) = o;
    }
  }
#pragma unroll
  for (int j = 0; j < 4; ++j) {
    redm[sy][(tx << 2) + j] = mACC[j];
    redz[sy][(tx << 2) + j] = zACC[j];
  }
  __syncthreads();
  if (tid < 64) {
    const float NEGINF2 = -__builtin_inff();
    float M = NEGINF2, Z = 0.f;
#pragma unroll
    for (int y = 0; y < 16; ++y) {
      float m = redm[y][tid], z = redz[y][tid];
      float Mn = fmaxf(M, m);
      Z = Z * expf(M - Mn) + z * expf(m - Mn);
      M = Mn;
    }
    marr[b * NT_ + t0 + tid] = M;
    rzarr[b * NT_ + t0 + tid] = 1.0f / Z;
  }
}

// ---------------- finalize: read val(-dist) -> p; write val/soft/rev --------
__global__ __launch_bounds__(256) void k_final4(
    const float* __restrict__ marr, const float* __restrict__ rzarr,
    const int* __restrict__ src_len, const int* __restrict__ mel_len,
    float* __restrict__ val, float* __restrict__ soft, float* __restrict__ rev) {
  const int idx = blockIdx.x;
  const int tt = idx & 31;
  const int st = (idx >> 5) & 7;
  const int b = idx >> 8;
  const int s0 = st << 6, t0 = tt << 6;
  __shared__ float pl[64][65];
  const int tid = threadIdx.x;
  const int sy = tid & 15, tx = tid >> 4;
  const int sl = src_len[b], ml = mel_len[b];
#pragma unroll
  for (int j = 0; j < 4; ++j) {
    const int t = t0 + (tx << 2) + j;
    const bool tvalid = t < ml;
    const float mv = marr[b * NT_ + t];
    const float rzv = rzarr[b * NT_ + t];
    float* vp = &val[((size_t)b * NT_ + t) * NS_ + s0 + (sy << 2)];
    float4 ov = *reinterpret_cast<const float4*>(vp);
    float4 p;
    p.x = tvalid ? expf(ov.x - mv) * rzv : 0.f;
    p.y = tvalid ? expf(ov.y - mv) * rzv : 0.f;
    p.z = tvalid ? expf(ov.z - mv) * rzv : 0.f;
    p.w = tvalid ? expf(ov.w - mv) * rzv : 0.f;
    *reinterpret_cast<float4*>(vp) = p;
    pl[(tx << 2) + j][(sy << 2) + 0] = p.x;
    pl[(tx << 2) + j][(sy << 2) + 1] = p.y;
    pl[(tx << 2) + j][(sy << 2) + 2] = p.z;
    pl[(tx << 2) + j][(sy << 2) + 3] = p.w;
  }
  __syncthreads();
  const int lane = tid & 63, w = tid >> 6;
#pragma unroll 4
  for (int i = 0; i < 16; ++i) {
    const int s_loc = (w << 4) + i;
    const int s = s0 + s_loc;
    float p = pl[lane][s_loc];
    size_t o = ((size_t)b * NS_ + s) * NT_ + t0 + lane;
    soft[o] = p;
    bool r = (s >= sl) || ((t0 + lane) >= ml);
    rev[o] = r ? 1.0f : 0.0f;
  }
}

// lane i <- lane i-1 via DPP wave_shr:1 (VALU, no LDS pipe). Lane 0 -> 0.
__device__ __forceinline__ float dp_shr1(float x) {
  int r = __builtin_amdgcn_update_dpp(0, __float_as_int(x), 0x138, 0xF, 0xF, true);
  return __int_as_float(r);
}

// RAW barrier: lgkmcnt(0) for cross-wave ds_write visibility, no vmcnt drain.
__device__ __forceinline__ void dp_bar() {
  asm volatile("s_waitcnt lgkmcnt(0)" ::: "memory");
  __builtin_amdgcn_sched_barrier(0);
  __builtin_amdgcn_s_barrier();
}

// Consumer chunk body: 16 rows, 4-row register batches. MASKED = apply (s<=t).
#define DP_CHUNK(MASKED)                                                      \
  _Pragma("unroll")                                                           \
  for (int rb8 = 0; rb8 < 4; ++rb8) {                                         \
    float4 d0[4], d1[4];                                                      \
    _Pragma("unroll")                                                         \
    for (int rr = 0; rr < 4; ++rr) {                                          \
      const float* rp = rowbase + (((rb8 << 2) + rr) << 9);                   \
      d0[rr] = *reinterpret_cast<const float4*>(rp + (lane << 2));            \
      d1[rr] = *reinterpret_cast<const float4*>(rp + 256 + (lane << 2));      \
    }                                                                         \
    _Pragma("unroll")                                                         \
    for (int rr = 0; rr < 4; ++rr) {                                          \
      const int t = tbase + (rb8 << 2) + rr;                                  \
      float cc[8] = {d0[rr].x, d0[rr].y, d0[rr].z, d0[rr].w,                  \
                     d1[rr].x, d1[rr].y, d1[rr].z, d1[rr].w};                 \
      const int sh = t & 31;                                                  \
      if (t < ml) {                                                           \
        float up = dp_shr1(v[7]);                                             \
        float prev = (lane == 0) ? NEGINF : up;                               \
        _Pragma("unroll")                                                     \
        for (int j = 0; j < 8; ++j) {                                         \
          float cur = v[j];                                                   \
          bool keep = cur >= prev;                                            \
          float vm = fmaxf(cur, prev);                                        \
          float vn;                                                           \
          if (MASKED) {                                                       \
            int s = (lane << 3) + j;                                          \
            vn = (s <= t) ? vm + cc[j] : NEGINF;                              \
          } else {                                                            \
            vn = vm + cc[j];                                                  \
          }                                                                   \
          uint32_t bit = keep ? 1u : inv[j];                                  \
          bw[j] |= bit << sh;                                                 \
          v[j] = vn;                                                          \
          prev = cur;                                                         \
        }                                                                     \
      } else {                                                                \
        _Pragma("unroll")                                                     \
        for (int j = 0; j < 8; ++j) bw[j] |= 1u << sh;                        \
      }                                                                       \
    }                                                                         \
  }

// ---------------- DP forward scan: 1 consumer + 2 reg-staging producer waves ----
__global__ __launch_bounds__(192) void k_dp(const float* __restrict__ val,
                                            const int* __restrict__ src_len,
                                            const int* __restrict__ mel_len,
                                            uint32_t* __restrict__ dir) {
  __shared__ float buf[2][16][512];  // 64 KB double buffer
  const int b = blockIdx.x;
  const int wv = threadIdx.x >> 6;   // 0 = consumer, 1..2 = producers
  const int lane = threadIdx.x & 63;
  const float* base = val + (size_t)b * NT_ * NS_;
  const int sl = src_len[b];
  const int ml = mel_len[b];
  const float NEGINF = -__builtin_inff();
  int ca = ((ml + 31) >> 5) << 1;
  const int C_act = ca > 128 ? 128 : ca;

  float4 ra[8], rb[8];
  const int r0 = (wv - 1) << 3;

  float v[8];
  uint32_t bw[8], inv[8];
#pragma unroll
  for (int j = 0; j < 8; ++j) {
    v[j] = 0.0f;
    bw[j] = 0u;
    int s = (lane << 3) + j;
    inv[j] = (s < sl) ? 0u : 1u;
  }

  if (wv > 0) {
#pragma unroll
    for (int rr = 0; rr < 8; ++rr) {
      const float* g = base + (size_t)(r0 + rr) * NS_;
      ra[rr] = *reinterpret_cast<const float4*>(g + (lane << 3));
      rb[rr] = *reinterpret_cast<const float4*>(g + (lane << 3) + 4);
    }
#pragma unroll
    for (int rr = 0; rr < 8; ++rr) {
      float* l = &buf[0][r0 + rr][0];
      *reinterpret_cast<float4*>(l + (lane << 2)) = ra[rr];
      *reinterpret_cast<float4*>(l + 256 + (lane << 2)) = rb[rr];
    }
#pragma unroll
    for (int rr = 0; rr < 8; ++rr) {
      const float* g = base + (size_t)(16 + r0 + rr) * NS_;
      ra[rr] = *reinterpret_cast<const float4*>(g + (lane << 3));
      rb[rr] = *reinterpret_cast<const float4*>(g + (lane << 3) + 4);
    }
  }
  dp_bar();

  for (int c = 0; c < C_act; ++c) {
    if (wv > 0) {
      if (c + 1 < C_act) {
        const int nb = (c + 1) & 1;
#pragma unroll
        for (int rr = 0; rr < 8; ++rr) {
          float* l = &buf[nb][r0 + rr][0];
          *reinterpret_cast<float4*>(l + (lane << 2)) = ra[rr];
          *reinterpret_cast<float4*>(l + 256 + (lane << 2)) = rb[rr];
        }
      }
      if (c + 2 < C_act) {
        const float* cb = base + ((size_t)(c + 2) * 16 + r0) * NS_;
#pragma unroll
        for (int rr = 0; rr < 8; ++rr) {
          const float* g = cb + (size_t)rr * NS_;
          ra[rr] = *reinterpret_cast<const float4*>(g + (lane << 3));
          rb[rr] = *reinterpret_cast<const float4*>(g + (lane << 3) + 4);
        }
      }
    } else {
      const float* rowbase = &buf[c & 1][0][0];
      const int tbase = c << 4;
      if (c < 32) {
        DP_CHUNK(true)
      } else {
        DP_CHUNK(false)
      }
      if (c & 1) {
        const int c32 = c >> 1;
#pragma unroll
        for (int j = 0; j < 8; ++j) {
          dir[((size_t)(b * NS_) + (lane << 3) + j) * 64 + c32] = bw[j];
          bw[j] = 0u;
        }
      }
    }
    dp_bar();
  }
  if (wv == 0) {
    for (int c32 = C_act >> 1; c32 < 64; ++c32) {
#pragma unroll
      for (int j = 0; j < 8; ++j)
        dir[((size_t)(b * NS_) + (lane << 3) + j) * 64 + c32] = 0xFFFFFFFFu;
    }
  }
}

// ---------------- backtrack: single phase, full-T bit plane in 128 KB LDS ----
__global__ __launch_bounds__(256) void k_backtrack(
    const uint32_t* __restrict__ dir, const int* __restrict__ src_len,
    const int* __restrict__ mel_len, float* __restrict__ hard) {
  __shared__ uint32_t dl[NS_ * 64];  // 128 KB
  const int b = blockIdx.x, tid = threadIdx.x;
  const uint32_t* db = dir + (size_t)b * NS_ * 64;
  for (int f = tid; f < 8192; f += 256) {
    int s = f >> 4;
    int wo = (f & 15) << 2;
    *reinterpret_cast<uint4*>(&dl[s * 64 + wo]) =
        *reinterpret_cast<const uint4*>(&db[s * 64 + wo]);
  }
  __syncthreads();
  if (tid == 0) {
    const int ml = mel_len[b];
    int idx = src_len[b] - 1;
    if (idx < 0) idx = 0;
    if (idx > NS_ - 1) idx = NS_ - 1;
    int cw = -1, ci = -1;
    uint32_t w = 0;
    for (int t = NT_ - 1; t >= 0; --t) {
      int wi = t >> 5;
      if (wi != cw || idx != ci) {
        w = dl[idx * 64 + wi];
        cw = wi;
        ci = idx;
      }
      if (t < ml) hard[((size_t)(b * NS_) + idx) * NT_ + t] = 1.0f;
      int step = (int)((w >> (t & 31)) & 1) - 1;
      idx += step;
      if (idx < 0) idx = 0;
    }
  }
}

// ---------------- host launch ----------------
extern "C" void kernel_launch(void* const* d_in, const int* in_sizes, int n_in,
                              void* d_out, int out_size, void* d_ws, size_t ws_size,
                              hipStream_t stream) {
  if (n_in != 17) return;
  if (ws_size < FULL_NEED) return;

  const float* text = (const float*)d_in[0];
  const float* mel = (const float*)d_in[1];
  const int* src_len = (const int*)d_in[2];
  const int* mel_len = (const int*)d_in[3];
  const float* tw1 = (const float*)d_in[7];
  const float* tb1 = (const float*)d_in[8];
  const float* tw2 = (const float*)d_in[9];
  const float* tb2 = (const float*)d_in[10];
  const float* mw1 = (const float*)d_in[11];
  const float* mb1 = (const float*)d_in[12];
  const float* mw2 = (const float*)d_in[13];
  const float* mb2 = (const float*)d_in[14];
  const float* mw3 = (const float*)d_in[15];
  const float* mb3 = (const float*)d_in[16];

  char* w8 = (char*)d_ws;
  float* melh1 = (float*)(w8 + 0);            // (B,T,160) 41.9 MB
  float* mh2 = (float*)(w8 + 41943040ull);    // (B,T,80)  21.0 MB
  float* texth1 = (float*)(w8 + 62914560ull); // (B,S,512) 33.5 MB
  float* val = (float*)(w8 + 0);              // (B,T,S) written after convs

  float* te = (float*)(w8 + P + PO_TE);
  float* me = (float*)(w8 + P + PO_ME);
  float* na = (float*)(w8 + P + PO_NA);
  float* nb = (float*)(w8 + P + PO_NB);
  float* marr = (float*)(w8 + P + PO_M);
  float* rzarr = (float*)(w8 + P + PO_RZ);
  float* wt1 = (float*)(w8 + P + PO_W1);
  float* wt2 = (float*)(w8 + P + PO_W2);
  float* wt3 = (float*)(w8 + P + PO_W3);
  float* wt4 = (float*)(w8 + P + PO_W4);
  float* wt5 = (float*)(w8 + P + PO_W5);
  uint32_t* dir = (uint32_t*)(w8 + P + PO_DIR);

  // outputs are float32
  float* soft = (float*)d_out;
  float* hard = soft + (size_t)NB_ * NS_ * NT_;
  float* rev = soft + 2 * (size_t)NB_ * NS_ * NT_;

  // weight transposes (f32 direct)
  k_wtrans<<<(512 * 256 * 3 + 255) / 256, 256, 0, stream>>>(tw1, wt1, 512, 256, 3, 512 * 256 * 3);
  k_wtrans<<<(80 * 512 + 255) / 256, 256, 0, stream>>>(tw2, wt2, 80, 512, 1, 80 * 512);
  k_wtrans<<<(160 * 80 * 3 + 255) / 256, 256, 0, stream>>>(mw1, wt3, 160, 80, 3, 160 * 80 * 3);
  k_wtrans<<<(80 * 160 * 3 + 255) / 256, 256, 0, stream>>>(mw2, wt4, 80, 160, 3, 80 * 160 * 3);
  k_wtrans<<<(80 * 80 + 255) / 256, 256, 0, stream>>>(mw3, wt5, 80, 80, 1, 80 * 80);

  // encoders (inputs read directly as f32); norms fused into final convs
  k_conv3<80, 160, 80, 5, 16, 11, 2><<<512 * 2, 256, 0, stream>>>(mel, wt3, mb1, melh1);
  k_conv3<160, 80, 80, 5, 32, 11, 2><<<512 * 1, 256, 0, stream>>>(melh1, wt4, mb2, mh2);
  k_conv<80, 80, 80, 5, 16, 11, 0, true, true><<<512 * 1, 256, 0, stream>>>(mh2, wt5, mb3, me, mel_len, nb);
  k_conv3<256, 512, 128, 8, 32, 9, 1><<<128 * 4, 256, 0, stream>>>(text, wt1, tb1, texth1);
  k_conv<512, 80, 80, 5, 32, 9, 0, true, true><<<128 * 1, 256, 0, stream>>>(texth1, wt2, tb2, te, src_len, na);

  // hard_A zero early (overlaps with stats2's compute window in the queue)
  hipMemsetAsync(hard, 0, (size_t)NB_ * NS_ * NT_ * 4, stream);

  // stats (+ val = masked -dist), then normalize/output pass
  k_stats2<<<NB_ * 32, 256, 0, stream>>>(te, me, na, nb, src_len, mel_len, marr, rzarr, val);
  k_final4<<<NB_ * 8 * 32, 256, 0, stream>>>(marr, rzarr, src_len, mel_len, val, soft, rev);

  // DP + backtrack
  k_dp<<<NB_, 192, 0, stream>>>(val, src_len, mel_len, dir);
  k_backtrack<<<NB_, 256, 0, stream>>>(dir, src_len, mel_len, hard);
}